// Round 17
// baseline (173.583 us; speedup 1.0000x reference)
//
#include <hip/hip_runtime.h>
#include <math.h>

#define BB   32
#define HH   56
#define WWI  56
#define CC   96
#define NHD  3
#define WSZ  7
#define SHF  3
#define NTK  49
#define NWIN 64
#define HDM  32
#define TOT  (BB*HH*WWI)               // 100352
#define QKSCALE 0.17677669529663687f
#define LEPS 1e-3f

typedef __attribute__((ext_vector_type(8))) short s8v;   // 8 bf16 (4 VGPRs)
typedef __attribute__((ext_vector_type(4))) float fx4;   // 4 fp32
typedef unsigned long long ull_t;

#define MFMA16(a,b,c) __builtin_amdgcn_mfma_f32_16x16x32_bf16((a),(b),(c),0,0,0)

__device__ __forceinline__ unsigned short f2bf(float f) {
    union { float f; unsigned u; } v; v.f = f;
    unsigned r = v.u + 0x7FFFu + ((v.u >> 16) & 1u);
    return (unsigned short)(r >> 16);
}

// sigmoid-form gelu (tanh approx): |err vs exact| <~2e-3, ~8 VALU ops vs ~28 for erff
__device__ __forceinline__ float gelu_t(float x) {
    float x3 = x * x * x;
    float z = -1.5957691216f * fmaf(0.044715f, x3, x);
    return x * __builtin_amdgcn_rcpf(1.f + __expf(z));
}

// windowed token id -> original flat token id (roll(-3,-3) + window partition)
__device__ __forceinline__ int wtok_to_orig(int wt) {
    int win = wt / NTK;
    int p   = wt - win * NTK;
    int b   = win >> 6;
    int w   = win & 63;
    int wi = w >> 3, wj = w & 7;
    int pi = p / WSZ, pj = p - pi * WSZ;
    int r = wi * WSZ + pi + SHF; if (r >= HH) r -= HH;
    int c = wj * WSZ + pj + SHF; if (c >= WWI) c -= WWI;
    return b * (HH * WWI) + r * WWI + c;
}

// LayerNorm in MFMA-A-fragment layout (reduction via shfl_xor 16/32)
__device__ __forceinline__ void ln_frag(const float* __restrict__ row,
                                        const float* __restrict__ gg,
                                        const float* __restrict__ bb,
                                        int g4, s8v ha[3])
{
    float h[24];
    #pragma unroll
    for (int ks = 0; ks < 3; ++ks) {
        fx4 v0 = *reinterpret_cast<const fx4*>(row + ks * 32 + g4 * 8);
        fx4 v1 = *reinterpret_cast<const fx4*>(row + ks * 32 + g4 * 8 + 4);
        h[ks*8+0]=v0.x; h[ks*8+1]=v0.y; h[ks*8+2]=v0.z; h[ks*8+3]=v0.w;
        h[ks*8+4]=v1.x; h[ks*8+5]=v1.y; h[ks*8+6]=v1.z; h[ks*8+7]=v1.w;
    }
    float s = 0.f, s2 = 0.f;
    #pragma unroll
    for (int j = 0; j < 24; ++j) { s += h[j]; s2 = fmaf(h[j], h[j], s2); }
    s  += __shfl_xor(s, 16);  s  += __shfl_xor(s, 32);
    s2 += __shfl_xor(s2, 16); s2 += __shfl_xor(s2, 32);
    const float mu = s * (1.f/CC);
    const float rs = rsqrtf(s2 * (1.f/CC) - mu * mu + LEPS);
    #pragma unroll
    for (int ks = 0; ks < 3; ++ks) {
        union { s8v v; unsigned short u[8]; } p;
        #pragma unroll
        for (int j = 0; j < 8; ++j) {
            int c = ks * 32 + g4 * 8 + j;
            p.u[j] = f2bf((h[ks*8+j] - mu) * rs * gg[c] + bb[c]);
        }
        ha[ks] = p.v;
    }
}

// ---------- P0: ALL weights frag-linearized (one wave-fragment = contiguous 1KB) ----------
extern "C" __global__ void p0_prep(const float* __restrict__ qw, const float* __restrict__ pw,
                                   const float* __restrict__ w1, const float* __restrict__ w2,
                                   const float* __restrict__ btab,
                                   unsigned short* __restrict__ wsw)
{
    int i = blockIdx.x * 256 + threadIdx.x;
    if (i < 27648) {                       // qwtf frag-linear
        int e = i & 7, f = i >> 3;
        int lane = f & 63, fid = f >> 6;   // fid 0..53
        int ks = fid % 3, t = fid / 3;
        int nt = t % 6, ck = t / 6;
        int n = ck * 96 + nt * 16 + (lane & 15);
        int k = ks * 32 + (lane >> 4) * 8 + e;
        float v = qw[k * 288 + n];
        if (n < 96) v *= QKSCALE;
        wsw[i] = f2bf(v);
    } else if (i < 36864) {                // pwtf frag-linear
        int j = i - 27648;
        int e = j & 7, f = j >> 3;
        int lane = f & 63, fid = f >> 6;   // fid 0..17
        int ks = fid % 3, nt = fid / 3;
        int n = nt * 16 + (lane & 15);
        int k = ks * 32 + (lane >> 4) * 8 + e;
        wsw[i] = f2bf(pw[k * 96 + n]);
    } else if (i < 73728) {                // w1f frag-linear
        int j = i - 36864;
        int e = j & 7, f = j >> 3;
        int lane = f & 63, fid = f >> 6;
        int ks = fid % 3, t = fid / 3;
        int nt = t & 3, ck = t >> 2;
        int n = ck * 64 + nt * 16 + (lane & 15);
        int k = ks * 32 + (lane >> 4) * 8 + e;
        wsw[i] = f2bf(w1[k * 384 + n]);
    } else if (i < 110592) {               // w2f frag-linear
        int j = i - 73728;
        int e = j & 7, f = j >> 3;
        int lane = f & 63, fid = f >> 6;
        int ks = fid & 1, t = fid >> 1;
        int nt = t % 6, ck = t / 6;
        int n = nt * 16 + (lane & 15);
        int k = ck * 64 + ks * 32 + (lane >> 4) * 8 + e;
        wsw[i] = f2bf(w2[k * 96 + n]);
    } else if (i < 148224) {               // BM table (fp32)
        float* bm = (float*)(wsw + 110592);
        int j = i - 110592;
        int n = j & 63, mh = j >> 6;
        int m = mh % 49, t = mh / 49;
        int hd = t % 3, cls = t / 3;       // cls = (wi==7)*2 + (wj==7)
        float val = 0.f;
        if (n < 49) {
            int it = m / 7, jt = m - it * 7;
            int iu = n / 7, ju = n - iu * 7;
            int li  = (cls & 2) ? (it < 4 ? 1 : 2) : 0;
            int lj  = (cls & 1) ? (jt < 4 ? 1 : 2) : 0;
            int lui = (cls & 2) ? (iu < 4 ? 1 : 2) : 0;
            int luj = (cls & 1) ? (ju < 4 ? 1 : 2) : 0;
            int bidx = (jt - ju + 6) * 13 + (it - iu + 6);
            val = btab[bidx * 3 + hd] + ((li*3+lj) == (lui*3+luj) ? 0.f : -100.f);
        }
        bm[j] = val;
    }
}

// ---------- K1: barrier-free gather + LN1(frag) + QKV MFMA -> qkvb bf16 ----------
extern "C" __global__ void __launch_bounds__(256, 6) k1_qkv(
    const float* __restrict__ x, const float* __restrict__ g1, const float* __restrict__ b1,
    const unsigned short* __restrict__ qwtf, const float* __restrict__ qb,
    unsigned short* __restrict__ qkvb)
{
    const int tid = threadIdx.x, wave = tid >> 6, lane = tid & 63;
    const int l15 = lane & 15, g4 = lane >> 4;
    const int row0 = blockIdx.x * 64 + wave * 16;

    s8v ha[3];
    {
        const int orig = wtok_to_orig(row0 + l15);
        ln_frag(x + (size_t)orig * CC, g1, b1, g4, ha);
    }

    #pragma unroll 1
    for (int ck = 0; ck < 3; ++ck) {
        fx4 acc[6];
        #pragma unroll
        for (int nt = 0; nt < 6; ++nt) acc[nt] = (fx4){0.f,0.f,0.f,0.f};
        #pragma unroll
        for (int ks = 0; ks < 3; ++ks) {
            #pragma unroll
            for (int nt = 0; nt < 6; ++nt) {
                s8v b = *reinterpret_cast<const s8v*>(
                    &qwtf[(((ck * 6 + nt) * 3 + ks) * 64 + lane) * 8]);
                acc[nt] = MFMA16(ha[ks], b, acc[nt]);
            }
        }
        const int rowb = row0 + g4 * 4;
        const float qmul = (ck == 0) ? QKSCALE : 1.f;   // qb scale matches scaled qwtf
        #pragma unroll
        for (int nt = 0; nt < 6; ++nt) {
            const int col = ck * 96 + nt * 16 + l15;
            const float qbc = qb[col] * qmul;
            #pragma unroll
            for (int r = 0; r < 4; ++r)
                qkvb[(size_t)(rowb + r) * 288 + col] = f2bf(acc[nt][r] + qbc);
        }
    }
}

// ---------- K2: MFMA attention on bf16 qkv ----------
extern "C" __global__ void __launch_bounds__(64, 3) k2_attn(
    unsigned short* __restrict__ qkvb, const float* __restrict__ bm)
{
    __shared__ unsigned short P[64][72];   // 9216 B
    const int lane = threadIdx.x;
    const int l15 = lane & 15, g4 = lane >> 4;
    const int task = blockIdx.x;
    const int win = task / 3, h = task - win * 3;
    const int g0  = win * NTK;
    const int w   = win & 63;
    const int cls = (((w >> 3) == 7) ? 2 : 0) + (((w & 7) == 7) ? 1 : 0);
    const float* BMh = bm + ((size_t)(cls * 3 + h)) * 49 * 64;

    s8v aq[4], bk[4];
    #pragma unroll
    for (int mt = 0; mt < 4; ++mt) {
        int tok = mt * 16 + l15; if (tok > 48) tok = 48;
        const unsigned short* qp = &qkvb[(size_t)(g0 + tok) * 288 + h * HDM + g4 * 8];
        aq[mt] = *reinterpret_cast<const s8v*>(qp);        // Q (pre-scaled)
        bk[mt] = *reinterpret_cast<const s8v*>(qp + 96);   // K
    }

    fx4 sc[4][4];
    #pragma unroll
    for (int mt = 0; mt < 4; ++mt)
        #pragma unroll
        for (int nt = 0; nt < 4; ++nt)
            sc[mt][nt] = MFMA16(aq[mt], bk[nt], ((fx4){0.f,0.f,0.f,0.f}));

    #pragma unroll
    for (int mt = 0; mt < 4; ++mt) {
        #pragma unroll
        for (int r = 0; r < 4; ++r) {
            const int m = mt * 16 + g4 * 4 + r;
            const int mc = m > 48 ? 48 : m;
            float rs1 = 0.f;
            #pragma unroll
            for (int nt = 0; nt < 4; ++nt) {
                const int n = nt * 16 + l15;
                float s = sc[mt][nt][r] + BMh[mc * 64 + n];
                float e = (n < NTK) ? __expf(s) : 0.f;
                sc[mt][nt][r] = e;
                rs1 += e;
            }
            rs1 += __shfl_xor(rs1, 1); rs1 += __shfl_xor(rs1, 2);
            rs1 += __shfl_xor(rs1, 4); rs1 += __shfl_xor(rs1, 8);
            const float iv1 = 1.f / rs1;
            float rs2 = 0.f;
            #pragma unroll
            for (int nt = 0; nt < 4; ++nt) {
                const int n = nt * 16 + l15;
                float e2 = (n < NTK) ? __expf(sc[mt][nt][r] * iv1) : 0.f;
                sc[mt][nt][r] = e2;
                rs2 += e2;
            }
            rs2 += __shfl_xor(rs2, 1); rs2 += __shfl_xor(rs2, 2);
            rs2 += __shfl_xor(rs2, 4); rs2 += __shfl_xor(rs2, 8);
            const float iv2 = 1.f / rs2;
            #pragma unroll
            for (int nt = 0; nt < 4; ++nt)
                P[m][nt * 16 + l15] = f2bf(sc[mt][nt][r] * iv2);
        }
    }
    __syncthreads();

    fx4 oc[4][2];
    #pragma unroll
    for (int mt = 0; mt < 4; ++mt) { oc[mt][0] = (fx4){0.f,0.f,0.f,0.f}; oc[mt][1] = (fx4){0.f,0.f,0.f,0.f}; }
    #pragma unroll
    for (int ks = 0; ks < 2; ++ks) {
        s8v vb[2];
        #pragma unroll
        for (int nt = 0; nt < 2; ++nt) {
            union { s8v v; unsigned short u[8]; } pv;
            #pragma unroll
            for (int j = 0; j < 8; ++j) {
                int tok = ks * 32 + g4 * 8 + j; if (tok > 48) tok = 48;
                pv.u[j] = qkvb[(size_t)(g0 + tok) * 288 + 192 + h * HDM + nt * 16 + l15];
            }
            vb[nt] = pv.v;
        }
        #pragma unroll
        for (int mt = 0; mt < 4; ++mt) {
            s8v pa = *reinterpret_cast<const s8v*>(&P[mt * 16 + l15][ks * 32 + g4 * 8]);
            oc[mt][0] = MFMA16(pa, vb[0], oc[mt][0]);
            oc[mt][1] = MFMA16(pa, vb[1], oc[mt][1]);
        }
    }
    #pragma unroll
    for (int mt = 0; mt < 4; ++mt) {
        #pragma unroll
        for (int r = 0; r < 4; ++r) {
            const int m = mt * 16 + g4 * 4 + r;
            if (m < NTK) {
                qkvb[(size_t)(g0 + m) * 288 + h * HDM + l15]      = f2bf(oc[mt][0][r]);
                qkvb[(size_t)(g0 + m) * 288 + h * HDM + 16 + l15] = f2bf(oc[mt][1][r]);
            }
        }
    }
}

// ---------- K2b: barrier-free proj GEMM + residual + un-shift scatter ----------
extern "C" __global__ void __launch_bounds__(256, 6) k2b_proj(
    const unsigned short* __restrict__ qkvb, const unsigned short* __restrict__ pwtf,
    const float* __restrict__ pb, const float* __restrict__ x, float* __restrict__ out)
{
    const int tid = threadIdx.x, wave = tid >> 6, lane = tid & 63;
    const int l15 = lane & 15, g4 = lane >> 4;
    const int row0 = blockIdx.x * 64 + wave * 16;

    const unsigned short* arow = qkvb + (size_t)(row0 + l15) * 288 + g4 * 8;
    s8v a[3];
    a[0] = *reinterpret_cast<const s8v*>(arow);
    a[1] = *reinterpret_cast<const s8v*>(arow + 32);
    a[2] = *reinterpret_cast<const s8v*>(arow + 64);

    fx4 acc[6];
    #pragma unroll
    for (int nt = 0; nt < 6; ++nt) acc[nt] = (fx4){0.f,0.f,0.f,0.f};
    #pragma unroll
    for (int ks = 0; ks < 3; ++ks) {
        #pragma unroll
        for (int nt = 0; nt < 6; ++nt) {
            s8v b = *reinterpret_cast<const s8v*>(&pwtf[((nt * 3 + ks) * 64 + lane) * 8]);
            acc[nt] = MFMA16(a[ks], b, acc[nt]);
        }
    }
    int orig[4];
    #pragma unroll
    for (int r = 0; r < 4; ++r)
        orig[r] = wtok_to_orig(row0 + g4 * 4 + r);
    #pragma unroll
    for (int nt = 0; nt < 6; ++nt) {
        const int col = nt * 16 + l15;
        const float pbc = pb[col];
        #pragma unroll
        for (int r = 0; r < 4; ++r) {
            const size_t idx = (size_t)orig[r] * CC + col;
            out[idx] = acc[nt][r] + pbc + x[idx];
        }
    }
}

// ---------- K3: barrier-free MLP (R15 single-tile form), occupancy uncapped ----------
#define LDA 72
extern "C" __global__ void __launch_bounds__(256, 6) k3_mlp(
    float* __restrict__ xio, const float* __restrict__ g2, const float* __restrict__ b2,
    const unsigned short* __restrict__ w1f, const float* __restrict__ bf1,
    const unsigned short* __restrict__ w2f, const float* __restrict__ bf2)
{
    __shared__ unsigned short Ac[64 * LDA];    // 9216 B, wave-private rows
    const int tid = threadIdx.x, wave = tid >> 6, lane = tid & 63;
    const int l15 = lane & 15, g4 = lane >> 4;
    const int row0 = blockIdx.x * 64 + wave * 16;

    s8v ha[3];
    ln_frag(xio + (size_t)(row0 + l15) * CC, g2, b2, g4, ha);

    fx4 oacc[6];
    #pragma unroll
    for (int nt = 0; nt < 6; ++nt) oacc[nt] = (fx4){0.f,0.f,0.f,0.f};

    #pragma unroll 1
    for (int ck = 0; ck < 6; ++ck) {
        // fc1: B-frags contiguous per wave (1KB coalesced loads)
        fx4 a1[4];
        #pragma unroll
        for (int nt = 0; nt < 4; ++nt) a1[nt] = (fx4){0.f,0.f,0.f,0.f};
        #pragma unroll
        for (int ks = 0; ks < 3; ++ks) {
            #pragma unroll
            for (int nt = 0; nt < 4; ++nt) {
                s8v b = *reinterpret_cast<const s8v*>(
                    &w1f[(((ck * 4 + nt) * 3 + ks) * 64 + lane) * 8]);
                a1[nt] = MFMA16(ha[ks], b, a1[nt]);
            }
        }
        // gelu^2 -> Ac (wave-private: in-wave lgkmcnt ordering suffices)
        #pragma unroll
        for (int nt = 0; nt < 4; ++nt) {
            const float bb = bf1[ck * 64 + nt * 16 + l15];
            #pragma unroll
            for (int r = 0; r < 4; ++r) {
                float v0 = a1[nt][r] + bb;
                Ac[(wave*16 + g4*4 + r) * LDA + nt*16 + l15] = f2bf(gelu_t(gelu_t(v0)));
            }
        }
        // fc2
        #pragma unroll
        for (int ks = 0; ks < 2; ++ks) {
            s8v a = *reinterpret_cast<const s8v*>(&Ac[(wave*16 + l15)*LDA + ks*32 + g4*8]);
            #pragma unroll
            for (int nt = 0; nt < 6; ++nt) {
                s8v b = *reinterpret_cast<const s8v*>(
                    &w2f[(((ck * 6 + nt) * 2 + ks) * 64 + lane) * 8]);
                oacc[nt] = MFMA16(a, b, oacc[nt]);
            }
        }
    }

    const int rowb = row0 + g4 * 4;
    #pragma unroll
    for (int nt = 0; nt < 6; ++nt) {
        const int col = nt * 16 + l15;
        const float bb = bf2[col];
        #pragma unroll
        for (int r = 0; r < 4; ++r) {
            const size_t idx = (size_t)(rowb + r) * CC + col;
            xio[idx] = xio[idx] + oacc[nt][r] + bb;
        }
    }
}

extern "C" void kernel_launch(void* const* d_in, const int* in_sizes, int n_in,
                              void* d_out, int out_size, void* d_ws, size_t ws_size,
                              hipStream_t stream)
{
    const float* x    = (const float*)d_in[0];
    const float* n1g  = (const float*)d_in[1];
    const float* n1b  = (const float*)d_in[2];
    const float* qw   = (const float*)d_in[3];
    const float* qb   = (const float*)d_in[4];
    const float* btab = (const float*)d_in[5];
    const float* pw   = (const float*)d_in[6];
    const float* pb   = (const float*)d_in[7];
    const float* n2g  = (const float*)d_in[8];
    const float* n2b  = (const float*)d_in[9];
    const float* w1   = (const float*)d_in[10];
    const float* bf1  = (const float*)d_in[11];
    const float* w2   = (const float*)d_in[12];
    const float* bf2  = (const float*)d_in[13];
    float* out = (float*)d_out;

    unsigned short* qkvb = (unsigned short*)d_ws;                 // TOT*288 bf16 = 57.8 MB
    unsigned short* wbf  = qkvb + (size_t)TOT * 288;
    unsigned short* qwtf = wbf;                                   // 27648 frag-linear
    unsigned short* pwtf = qwtf + 27648;                          // 9216 frag-linear
    unsigned short* w1f  = pwtf + 9216;                           // 36864 frag-linear
    unsigned short* w2f  = w1f + 36864;                           // 36864 frag-linear
    float* bmt = (float*)(wbf + 110592);                          // [4][3][49][64]

    p0_prep <<<579, 256, 0, stream>>>(qw, pw, w1, w2, btab, wbf);
    k1_qkv  <<<TOT/64, 256, 0, stream>>>(x, n1g, n1b, qwtf, qb, qkvb);
    k2_attn <<<BB*NWIN*NHD, 64, 0, stream>>>(qkvb, bmt);
    k2b_proj<<<TOT/64, 256, 0, stream>>>(qkvb, pwtf, pb, x, out);
    k3_mlp  <<<TOT/64, 256, 0, stream>>>(out, n2g, n2b, w1f, bf1, w2f, bf2);
}

// Round 18
// 148.871 us; speedup vs baseline: 1.1660x; 1.1660x over previous
//
#include <hip/hip_runtime.h>
#include <math.h>

#define BB   32
#define HH   56
#define WWI  56
#define CC   96
#define NHD  3
#define WSZ  7
#define SHF  3
#define NTK  49
#define NWIN 64
#define HDM  32
#define TOT  (BB*HH*WWI)               // 100352
#define QKSCALE 0.17677669529663687f
#define LEPS 1e-3f

typedef __attribute__((ext_vector_type(8))) short s8v;   // 8 bf16 (4 VGPRs)
typedef __attribute__((ext_vector_type(4))) float fx4;   // 4 fp32
typedef unsigned long long ull_t;

#define MFMA16(a,b,c) __builtin_amdgcn_mfma_f32_16x16x32_bf16((a),(b),(c),0,0,0)

__device__ __forceinline__ unsigned short f2bf(float f) {
    union { float f; unsigned u; } v; v.f = f;
    unsigned r = v.u + 0x7FFFu + ((v.u >> 16) & 1u);
    return (unsigned short)(r >> 16);
}

// sigmoid-form gelu (tanh approx): |err vs exact| <~2e-3, ~8 VALU ops vs ~28 for erff
__device__ __forceinline__ float gelu_t(float x) {
    float x3 = x * x * x;
    float z = -1.5957691216f * fmaf(0.044715f, x3, x);
    return x * __builtin_amdgcn_rcpf(1.f + __expf(z));
}

// windowed token id -> original flat token id (roll(-3,-3) + window partition)
__device__ __forceinline__ int wtok_to_orig(int wt) {
    int win = wt / NTK;
    int p   = wt - win * NTK;
    int b   = win >> 6;
    int w   = win & 63;
    int wi = w >> 3, wj = w & 7;
    int pi = p / WSZ, pj = p - pi * WSZ;
    int r = wi * WSZ + pi + SHF; if (r >= HH) r -= HH;
    int c = wj * WSZ + pj + SHF; if (c >= WWI) c -= WWI;
    return b * (HH * WWI) + r * WWI + c;
}

// LayerNorm in MFMA-A-fragment layout (reduction via shfl_xor 16/32)
__device__ __forceinline__ void ln_frag(const float* __restrict__ row,
                                        const float* __restrict__ gg,
                                        const float* __restrict__ bb,
                                        int g4, s8v ha[3])
{
    float h[24];
    #pragma unroll
    for (int ks = 0; ks < 3; ++ks) {
        fx4 v0 = *reinterpret_cast<const fx4*>(row + ks * 32 + g4 * 8);
        fx4 v1 = *reinterpret_cast<const fx4*>(row + ks * 32 + g4 * 8 + 4);
        h[ks*8+0]=v0.x; h[ks*8+1]=v0.y; h[ks*8+2]=v0.z; h[ks*8+3]=v0.w;
        h[ks*8+4]=v1.x; h[ks*8+5]=v1.y; h[ks*8+6]=v1.z; h[ks*8+7]=v1.w;
    }
    float s = 0.f, s2 = 0.f;
    #pragma unroll
    for (int j = 0; j < 24; ++j) { s += h[j]; s2 = fmaf(h[j], h[j], s2); }
    s  += __shfl_xor(s, 16);  s  += __shfl_xor(s, 32);
    s2 += __shfl_xor(s2, 16); s2 += __shfl_xor(s2, 32);
    const float mu = s * (1.f/CC);
    const float rs = rsqrtf(s2 * (1.f/CC) - mu * mu + LEPS);
    #pragma unroll
    for (int ks = 0; ks < 3; ++ks) {
        union { s8v v; unsigned short u[8]; } p;
        #pragma unroll
        for (int j = 0; j < 8; ++j) {
            int c = ks * 32 + g4 * 8 + j;
            p.u[j] = f2bf((h[ks*8+j] - mu) * rs * gg[c] + bb[c]);
        }
        ha[ks] = p.v;
    }
}

// ---------- P0: ALL weights frag-linearized (one wave-fragment = contiguous 1KB) ----------
extern "C" __global__ void p0_prep(const float* __restrict__ qw, const float* __restrict__ pw,
                                   const float* __restrict__ w1, const float* __restrict__ w2,
                                   const float* __restrict__ btab,
                                   unsigned short* __restrict__ wsw)
{
    int i = blockIdx.x * 256 + threadIdx.x;
    if (i < 27648) {                       // qwtf frag-linear
        int e = i & 7, f = i >> 3;
        int lane = f & 63, fid = f >> 6;   // fid 0..53
        int ks = fid % 3, t = fid / 3;
        int nt = t % 6, ck = t / 6;
        int n = ck * 96 + nt * 16 + (lane & 15);
        int k = ks * 32 + (lane >> 4) * 8 + e;
        float v = qw[k * 288 + n];
        if (n < 96) v *= QKSCALE;
        wsw[i] = f2bf(v);
    } else if (i < 36864) {                // pwtf frag-linear
        int j = i - 27648;
        int e = j & 7, f = j >> 3;
        int lane = f & 63, fid = f >> 6;   // fid 0..17
        int ks = fid % 3, nt = fid / 3;
        int n = nt * 16 + (lane & 15);
        int k = ks * 32 + (lane >> 4) * 8 + e;
        wsw[i] = f2bf(pw[k * 96 + n]);
    } else if (i < 73728) {                // w1f frag-linear
        int j = i - 36864;
        int e = j & 7, f = j >> 3;
        int lane = f & 63, fid = f >> 6;
        int ks = fid % 3, t = fid / 3;
        int nt = t & 3, ck = t >> 2;
        int n = ck * 64 + nt * 16 + (lane & 15);
        int k = ks * 32 + (lane >> 4) * 8 + e;
        wsw[i] = f2bf(w1[k * 384 + n]);
    } else if (i < 110592) {               // w2f frag-linear
        int j = i - 73728;
        int e = j & 7, f = j >> 3;
        int lane = f & 63, fid = f >> 6;
        int ks = fid & 1, t = fid >> 1;
        int nt = t % 6, ck = t / 6;
        int n = nt * 16 + (lane & 15);
        int k = ck * 64 + ks * 32 + (lane >> 4) * 8 + e;
        wsw[i] = f2bf(w2[k * 96 + n]);
    } else if (i < 148224) {               // BM table (fp32)
        float* bm = (float*)(wsw + 110592);
        int j = i - 110592;
        int n = j & 63, mh = j >> 6;
        int m = mh % 49, t = mh / 49;
        int hd = t % 3, cls = t / 3;       // cls = (wi==7)*2 + (wj==7)
        float val = 0.f;
        if (n < 49) {
            int it = m / 7, jt = m - it * 7;
            int iu = n / 7, ju = n - iu * 7;
            int li  = (cls & 2) ? (it < 4 ? 1 : 2) : 0;
            int lj  = (cls & 1) ? (jt < 4 ? 1 : 2) : 0;
            int lui = (cls & 2) ? (iu < 4 ? 1 : 2) : 0;
            int luj = (cls & 1) ? (ju < 4 ? 1 : 2) : 0;
            int bidx = (jt - ju + 6) * 13 + (it - iu + 6);
            val = btab[bidx * 3 + hd] + ((li*3+lj) == (lui*3+luj) ? 0.f : -100.f);
        }
        bm[j] = val;
    }
}

// ---------- K1: barrier-free gather + LN1(frag) + QKV MFMA -> qkvb bf16 ----------
// ck loop fully unrolled: no barriers -> compiler can pipeline weight loads
// across iterations (cross-ck prefetch under MFMA/store tail).
extern "C" __global__ void __launch_bounds__(256, 3) k1_qkv(
    const float* __restrict__ x, const float* __restrict__ g1, const float* __restrict__ b1,
    const unsigned short* __restrict__ qwtf, const float* __restrict__ qb,
    unsigned short* __restrict__ qkvb)
{
    const int tid = threadIdx.x, wave = tid >> 6, lane = tid & 63;
    const int l15 = lane & 15, g4 = lane >> 4;
    const int row0 = blockIdx.x * 64 + wave * 16;

    s8v ha[3];
    {
        const int orig = wtok_to_orig(row0 + l15);
        ln_frag(x + (size_t)orig * CC, g1, b1, g4, ha);
    }

    #pragma unroll
    for (int ck = 0; ck < 3; ++ck) {
        fx4 acc[6];
        #pragma unroll
        for (int nt = 0; nt < 6; ++nt) acc[nt] = (fx4){0.f,0.f,0.f,0.f};
        #pragma unroll
        for (int ks = 0; ks < 3; ++ks) {
            #pragma unroll
            for (int nt = 0; nt < 6; ++nt) {
                s8v b = *reinterpret_cast<const s8v*>(
                    &qwtf[(((ck * 6 + nt) * 3 + ks) * 64 + lane) * 8]);
                acc[nt] = MFMA16(ha[ks], b, acc[nt]);
            }
        }
        const int rowb = row0 + g4 * 4;
        const float qmul = (ck == 0) ? QKSCALE : 1.f;   // qb scale matches scaled qwtf
        #pragma unroll
        for (int nt = 0; nt < 6; ++nt) {
            const int col = ck * 96 + nt * 16 + l15;
            const float qbc = qb[col] * qmul;
            #pragma unroll
            for (int r = 0; r < 4; ++r)
                qkvb[(size_t)(rowb + r) * 288 + col] = f2bf(acc[nt][r] + qbc);
        }
    }
}

// ---------- K2: MFMA attention on bf16 qkv (R12/R15 form) ----------
extern "C" __global__ void __launch_bounds__(64, 2) k2_attn(
    unsigned short* __restrict__ qkvb, const float* __restrict__ bm)
{
    __shared__ unsigned short P[64][72];   // 9216 B
    const int lane = threadIdx.x;
    const int l15 = lane & 15, g4 = lane >> 4;
    const int task = blockIdx.x;
    const int win = task / 3, h = task - win * 3;
    const int g0  = win * NTK;
    const int w   = win & 63;
    const int cls = (((w >> 3) == 7) ? 2 : 0) + (((w & 7) == 7) ? 1 : 0);
    const float* BMh = bm + ((size_t)(cls * 3 + h)) * 49 * 64;

    s8v aq[4], bk[4];
    #pragma unroll
    for (int mt = 0; mt < 4; ++mt) {
        int tok = mt * 16 + l15; if (tok > 48) tok = 48;
        const unsigned short* qp = &qkvb[(size_t)(g0 + tok) * 288 + h * HDM + g4 * 8];
        aq[mt] = *reinterpret_cast<const s8v*>(qp);        // Q (pre-scaled)
        bk[mt] = *reinterpret_cast<const s8v*>(qp + 96);   // K
    }

    fx4 sc[4][4];
    #pragma unroll
    for (int mt = 0; mt < 4; ++mt)
        #pragma unroll
        for (int nt = 0; nt < 4; ++nt)
            sc[mt][nt] = MFMA16(aq[mt], bk[nt], ((fx4){0.f,0.f,0.f,0.f}));

    #pragma unroll
    for (int mt = 0; mt < 4; ++mt) {
        #pragma unroll
        for (int r = 0; r < 4; ++r) {
            const int m = mt * 16 + g4 * 4 + r;
            const int mc = m > 48 ? 48 : m;
            float rs1 = 0.f;
            #pragma unroll
            for (int nt = 0; nt < 4; ++nt) {
                const int n = nt * 16 + l15;
                float s = sc[mt][nt][r] + BMh[mc * 64 + n];
                float e = (n < NTK) ? __expf(s) : 0.f;
                sc[mt][nt][r] = e;
                rs1 += e;
            }
            rs1 += __shfl_xor(rs1, 1); rs1 += __shfl_xor(rs1, 2);
            rs1 += __shfl_xor(rs1, 4); rs1 += __shfl_xor(rs1, 8);
            const float iv1 = 1.f / rs1;
            float rs2 = 0.f;
            #pragma unroll
            for (int nt = 0; nt < 4; ++nt) {
                const int n = nt * 16 + l15;
                float e2 = (n < NTK) ? __expf(sc[mt][nt][r] * iv1) : 0.f;
                sc[mt][nt][r] = e2;
                rs2 += e2;
            }
            rs2 += __shfl_xor(rs2, 1); rs2 += __shfl_xor(rs2, 2);
            rs2 += __shfl_xor(rs2, 4); rs2 += __shfl_xor(rs2, 8);
            const float iv2 = 1.f / rs2;
            #pragma unroll
            for (int nt = 0; nt < 4; ++nt)
                P[m][nt * 16 + l15] = f2bf(sc[mt][nt][r] * iv2);
        }
    }
    __syncthreads();

    fx4 oc[4][2];
    #pragma unroll
    for (int mt = 0; mt < 4; ++mt) { oc[mt][0] = (fx4){0.f,0.f,0.f,0.f}; oc[mt][1] = (fx4){0.f,0.f,0.f,0.f}; }
    #pragma unroll
    for (int ks = 0; ks < 2; ++ks) {
        s8v vb[2];
        #pragma unroll
        for (int nt = 0; nt < 2; ++nt) {
            union { s8v v; unsigned short u[8]; } pv;
            #pragma unroll
            for (int j = 0; j < 8; ++j) {
                int tok = ks * 32 + g4 * 8 + j; if (tok > 48) tok = 48;
                pv.u[j] = qkvb[(size_t)(g0 + tok) * 288 + 192 + h * HDM + nt * 16 + l15];
            }
            vb[nt] = pv.v;
        }
        #pragma unroll
        for (int mt = 0; mt < 4; ++mt) {
            s8v pa = *reinterpret_cast<const s8v*>(&P[mt * 16 + l15][ks * 32 + g4 * 8]);
            oc[mt][0] = MFMA16(pa, vb[0], oc[mt][0]);
            oc[mt][1] = MFMA16(pa, vb[1], oc[mt][1]);
        }
    }
    #pragma unroll
    for (int mt = 0; mt < 4; ++mt) {
        #pragma unroll
        for (int r = 0; r < 4; ++r) {
            const int m = mt * 16 + g4 * 4 + r;
            if (m < NTK) {
                qkvb[(size_t)(g0 + m) * 288 + h * HDM + l15]      = f2bf(oc[mt][0][r]);
                qkvb[(size_t)(g0 + m) * 288 + h * HDM + 16 + l15] = f2bf(oc[mt][1][r]);
            }
        }
    }
}

// ---------- K2b: barrier-free proj GEMM + residual + un-shift scatter ----------
extern "C" __global__ void __launch_bounds__(256, 3) k2b_proj(
    const unsigned short* __restrict__ qkvb, const unsigned short* __restrict__ pwtf,
    const float* __restrict__ pb, const float* __restrict__ x, float* __restrict__ out)
{
    const int tid = threadIdx.x, wave = tid >> 6, lane = tid & 63;
    const int l15 = lane & 15, g4 = lane >> 4;
    const int row0 = blockIdx.x * 64 + wave * 16;

    const unsigned short* arow = qkvb + (size_t)(row0 + l15) * 288 + g4 * 8;
    s8v a[3];
    a[0] = *reinterpret_cast<const s8v*>(arow);
    a[1] = *reinterpret_cast<const s8v*>(arow + 32);
    a[2] = *reinterpret_cast<const s8v*>(arow + 64);

    fx4 acc[6];
    #pragma unroll
    for (int nt = 0; nt < 6; ++nt) acc[nt] = (fx4){0.f,0.f,0.f,0.f};
    #pragma unroll
    for (int ks = 0; ks < 3; ++ks) {
        #pragma unroll
        for (int nt = 0; nt < 6; ++nt) {
            s8v b = *reinterpret_cast<const s8v*>(&pwtf[((nt * 3 + ks) * 64 + lane) * 8]);
            acc[nt] = MFMA16(a[ks], b, acc[nt]);
        }
    }
    int orig[4];
    #pragma unroll
    for (int r = 0; r < 4; ++r)
        orig[r] = wtok_to_orig(row0 + g4 * 4 + r);
    #pragma unroll
    for (int nt = 0; nt < 6; ++nt) {
        const int col = nt * 16 + l15;
        const float pbc = pb[col];
        #pragma unroll
        for (int r = 0; r < 4; ++r) {
            const size_t idx = (size_t)orig[r] * CC + col;
            out[idx] = acc[nt][r] + pbc + x[idx];
        }
    }
}

// ---------- K3: barrier-free MLP (R15 form) + full ck unroll ----------
// Removing '#pragma unroll 1' lets the scheduler hoist ck+1 weight loads
// above ck's gelu/fc2 tail (no barriers to fence them; 170-reg budget).
#define LDA 72
extern "C" __global__ void __launch_bounds__(256, 3) k3_mlp(
    float* __restrict__ xio, const float* __restrict__ g2, const float* __restrict__ b2,
    const unsigned short* __restrict__ w1f, const float* __restrict__ bf1,
    const unsigned short* __restrict__ w2f, const float* __restrict__ bf2)
{
    __shared__ unsigned short Ac[64 * LDA];    // 9216 B, wave-private rows
    const int tid = threadIdx.x, wave = tid >> 6, lane = tid & 63;
    const int l15 = lane & 15, g4 = lane >> 4;
    const int row0 = blockIdx.x * 64 + wave * 16;

    s8v ha[3];
    ln_frag(xio + (size_t)(row0 + l15) * CC, g2, b2, g4, ha);

    fx4 oacc[6];
    #pragma unroll
    for (int nt = 0; nt < 6; ++nt) oacc[nt] = (fx4){0.f,0.f,0.f,0.f};

    #pragma unroll
    for (int ck = 0; ck < 6; ++ck) {
        // fc1: B-frags contiguous per wave (1KB coalesced loads)
        fx4 a1[4];
        #pragma unroll
        for (int nt = 0; nt < 4; ++nt) a1[nt] = (fx4){0.f,0.f,0.f,0.f};
        #pragma unroll
        for (int ks = 0; ks < 3; ++ks) {
            #pragma unroll
            for (int nt = 0; nt < 4; ++nt) {
                s8v b = *reinterpret_cast<const s8v*>(
                    &w1f[(((ck * 4 + nt) * 3 + ks) * 64 + lane) * 8]);
                a1[nt] = MFMA16(ha[ks], b, a1[nt]);
            }
        }
        // gelu^2 -> Ac (wave-private: in-wave lgkmcnt ordering suffices)
        #pragma unroll
        for (int nt = 0; nt < 4; ++nt) {
            const float bb = bf1[ck * 64 + nt * 16 + l15];
            #pragma unroll
            for (int r = 0; r < 4; ++r) {
                float v0 = a1[nt][r] + bb;
                Ac[(wave*16 + g4*4 + r) * LDA + nt*16 + l15] = f2bf(gelu_t(gelu_t(v0)));
            }
        }
        // fc2
        #pragma unroll
        for (int ks = 0; ks < 2; ++ks) {
            s8v a = *reinterpret_cast<const s8v*>(&Ac[(wave*16 + l15)*LDA + ks*32 + g4*8]);
            #pragma unroll
            for (int nt = 0; nt < 6; ++nt) {
                s8v b = *reinterpret_cast<const s8v*>(
                    &w2f[(((ck * 6 + nt) * 2 + ks) * 64 + lane) * 8]);
                oacc[nt] = MFMA16(a, b, oacc[nt]);
            }
        }
    }

    const int rowb = row0 + g4 * 4;
    #pragma unroll
    for (int nt = 0; nt < 6; ++nt) {
        const int col = nt * 16 + l15;
        const float bb = bf2[col];
        #pragma unroll
        for (int r = 0; r < 4; ++r) {
            const size_t idx = (size_t)(rowb + r) * CC + col;
            xio[idx] = xio[idx] + oacc[nt][r] + bb;
        }
    }
}

extern "C" void kernel_launch(void* const* d_in, const int* in_sizes, int n_in,
                              void* d_out, int out_size, void* d_ws, size_t ws_size,
                              hipStream_t stream)
{
    const float* x    = (const float*)d_in[0];
    const float* n1g  = (const float*)d_in[1];
    const float* n1b  = (const float*)d_in[2];
    const float* qw   = (const float*)d_in[3];
    const float* qb   = (const float*)d_in[4];
    const float* btab = (const float*)d_in[5];
    const float* pw   = (const float*)d_in[6];
    const float* pb   = (const float*)d_in[7];
    const float* n2g  = (const float*)d_in[8];
    const float* n2b  = (const float*)d_in[9];
    const float* w1   = (const float*)d_in[10];
    const float* bf1  = (const float*)d_in[11];
    const float* w2   = (const float*)d_in[12];
    const float* bf2  = (const float*)d_in[13];
    float* out = (float*)d_out;

    unsigned short* qkvb = (unsigned short*)d_ws;                 // TOT*288 bf16 = 57.8 MB
    unsigned short* wbf  = qkvb + (size_t)TOT * 288;
    unsigned short* qwtf = wbf;                                   // 27648 frag-linear
    unsigned short* pwtf = qwtf + 27648;                          // 9216 frag-linear
    unsigned short* w1f  = pwtf + 9216;                           // 36864 frag-linear
    unsigned short* w2f  = w1f + 36864;                           // 36864 frag-linear
    float* bmt = (float*)(wbf + 110592);                          // [4][3][49][64]

    p0_prep <<<579, 256, 0, stream>>>(qw, pw, w1, w2, btab, wbf);
    k1_qkv  <<<TOT/64, 256, 0, stream>>>(x, n1g, n1b, qwtf, qb, qkvb);
    k2_attn <<<BB*NWIN*NHD, 64, 0, stream>>>(qkvb, bmt);
    k2b_proj<<<TOT/64, 256, 0, stream>>>(qkvb, pwtf, pb, x, out);
    k3_mlp  <<<TOT/64, 256, 0, stream>>>(out, n2g, n2b, w1f, bf1, w2f, bf2);
}

// Round 19
// 144.696 us; speedup vs baseline: 1.1996x; 1.0288x over previous
//
#include <hip/hip_runtime.h>
#include <math.h>

#define BB   32
#define HH   56
#define WWI  56
#define CC   96
#define NHD  3
#define WSZ  7
#define SHF  3
#define NTK  49
#define NWIN 64
#define HDM  32
#define TOT  (BB*HH*WWI)               // 100352
#define QKSCALE 0.17677669529663687f
#define LEPS 1e-3f

typedef __attribute__((ext_vector_type(8))) short s8v;   // 8 bf16 (4 VGPRs)
typedef __attribute__((ext_vector_type(4))) float fx4;   // 4 fp32
typedef unsigned long long ull_t;

#define MFMA16(a,b,c) __builtin_amdgcn_mfma_f32_16x16x32_bf16((a),(b),(c),0,0,0)

__device__ __forceinline__ unsigned short f2bf(float f) {
    union { float f; unsigned u; } v; v.f = f;
    unsigned r = v.u + 0x7FFFu + ((v.u >> 16) & 1u);
    return (unsigned short)(r >> 16);
}

// sigmoid-form gelu (tanh approx): |err vs exact| <~2e-3, ~8 VALU ops vs ~28 for erff
__device__ __forceinline__ float gelu_t(float x) {
    float x3 = x * x * x;
    float z = -1.5957691216f * fmaf(0.044715f, x3, x);
    return x * __builtin_amdgcn_rcpf(1.f + __expf(z));
}

// windowed token id -> original flat token id (roll(-3,-3) + window partition)
__device__ __forceinline__ int wtok_to_orig(int wt) {
    int win = wt / NTK;
    int p   = wt - win * NTK;
    int b   = win >> 6;
    int w   = win & 63;
    int wi = w >> 3, wj = w & 7;
    int pi = p / WSZ, pj = p - pi * WSZ;
    int r = wi * WSZ + pi + SHF; if (r >= HH) r -= HH;
    int c = wj * WSZ + pj + SHF; if (c >= WWI) c -= WWI;
    return b * (HH * WWI) + r * WWI + c;
}

// LayerNorm in MFMA-A-fragment layout (reduction via shfl_xor 16/32)
__device__ __forceinline__ void ln_frag(const float* __restrict__ row,
                                        const float* __restrict__ gg,
                                        const float* __restrict__ bb,
                                        int g4, s8v ha[3])
{
    float h[24];
    #pragma unroll
    for (int ks = 0; ks < 3; ++ks) {
        fx4 v0 = *reinterpret_cast<const fx4*>(row + ks * 32 + g4 * 8);
        fx4 v1 = *reinterpret_cast<const fx4*>(row + ks * 32 + g4 * 8 + 4);
        h[ks*8+0]=v0.x; h[ks*8+1]=v0.y; h[ks*8+2]=v0.z; h[ks*8+3]=v0.w;
        h[ks*8+4]=v1.x; h[ks*8+5]=v1.y; h[ks*8+6]=v1.z; h[ks*8+7]=v1.w;
    }
    float s = 0.f, s2 = 0.f;
    #pragma unroll
    for (int j = 0; j < 24; ++j) { s += h[j]; s2 = fmaf(h[j], h[j], s2); }
    s  += __shfl_xor(s, 16);  s  += __shfl_xor(s, 32);
    s2 += __shfl_xor(s2, 16); s2 += __shfl_xor(s2, 32);
    const float mu = s * (1.f/CC);
    const float rs = rsqrtf(s2 * (1.f/CC) - mu * mu + LEPS);
    #pragma unroll
    for (int ks = 0; ks < 3; ++ks) {
        union { s8v v; unsigned short u[8]; } p;
        #pragma unroll
        for (int j = 0; j < 8; ++j) {
            int c = ks * 32 + g4 * 8 + j;
            p.u[j] = f2bf((h[ks*8+j] - mu) * rs * gg[c] + bb[c]);
        }
        ha[ks] = p.v;
    }
}

// ---------- P0: weights frag-linearized + BM in D-fragment layout ----------
// bmf[(cls*3+h)*4096 + (mt*4+nt)*256 + lane*4 + r] = bias+mask for
//   m = clamp(mt*16+(lane>>4)*4+r, 48), n = nt*16+(lane&15)
extern "C" __global__ void p0_prep(const float* __restrict__ qw, const float* __restrict__ pw,
                                   const float* __restrict__ w1, const float* __restrict__ w2,
                                   const float* __restrict__ btab,
                                   unsigned short* __restrict__ wsw)
{
    int i = blockIdx.x * 256 + threadIdx.x;
    if (i < 27648) {                       // qwtf frag-linear
        int e = i & 7, f = i >> 3;
        int lane = f & 63, fid = f >> 6;   // fid 0..53
        int ks = fid % 3, t = fid / 3;
        int nt = t % 6, ck = t / 6;
        int n = ck * 96 + nt * 16 + (lane & 15);
        int k = ks * 32 + (lane >> 4) * 8 + e;
        float v = qw[k * 288 + n];
        if (n < 96) v *= QKSCALE;
        wsw[i] = f2bf(v);
    } else if (i < 36864) {                // pwtf frag-linear
        int j = i - 27648;
        int e = j & 7, f = j >> 3;
        int lane = f & 63, fid = f >> 6;   // fid 0..17
        int ks = fid % 3, nt = fid / 3;
        int n = nt * 16 + (lane & 15);
        int k = ks * 32 + (lane >> 4) * 8 + e;
        wsw[i] = f2bf(pw[k * 96 + n]);
    } else if (i < 73728) {                // w1f frag-linear
        int j = i - 36864;
        int e = j & 7, f = j >> 3;
        int lane = f & 63, fid = f >> 6;
        int ks = fid % 3, t = fid / 3;
        int nt = t & 3, ck = t >> 2;
        int n = ck * 64 + nt * 16 + (lane & 15);
        int k = ks * 32 + (lane >> 4) * 8 + e;
        wsw[i] = f2bf(w1[k * 384 + n]);
    } else if (i < 110592) {               // w2f frag-linear
        int j = i - 73728;
        int e = j & 7, f = j >> 3;
        int lane = f & 63, fid = f >> 6;
        int ks = fid & 1, t = fid >> 1;
        int nt = t % 6, ck = t / 6;
        int n = nt * 16 + (lane & 15);
        int k = ck * 64 + ks * 32 + (lane >> 4) * 8 + e;
        wsw[i] = f2bf(w2[k * 96 + n]);
    } else if (i < 159744) {               // bmf: BM in D-frag layout (fp32)
        float* bmf = (float*)(wsw + 110592);
        int j = i - 110592;                // 0..49151
        int r = j & 3, lane = (j >> 2) & 63;
        int fid = j >> 8;                  // 0..191
        int mtnt = fid & 15, t = fid >> 4; // t 0..11
        int mt = mtnt >> 2, nt = mtnt & 3;
        int hd = t % 3, cls = t / 3;
        int m = mt * 16 + (lane >> 4) * 4 + r; if (m > 48) m = 48;
        int n = nt * 16 + (lane & 15);
        float val = 0.f;
        if (n < 49) {
            int it = m / 7, jt = m - it * 7;
            int iu = n / 7, ju = n - iu * 7;
            int li  = (cls & 2) ? (it < 4 ? 1 : 2) : 0;
            int lj  = (cls & 1) ? (jt < 4 ? 1 : 2) : 0;
            int lui = (cls & 2) ? (iu < 4 ? 1 : 2) : 0;
            int luj = (cls & 1) ? (ju < 4 ? 1 : 2) : 0;
            int bidx = (jt - ju + 6) * 13 + (it - iu + 6);
            val = btab[bidx * 3 + hd] + ((li*3+lj) == (lui*3+luj) ? 0.f : -100.f);
        }
        bmf[j] = val;
    }
}

// ---------- K1: barrier-free gather + LN1(frag) + QKV MFMA ----------
// Q,K -> qkvb[tok][0..191]; V -> vF in MFMA-fragment order (k2 reads 1KB frags).
// ck loop fully unrolled (R18: +9us on k1 via cross-ck load pipelining).
extern "C" __global__ void __launch_bounds__(256, 3) k1_qkv(
    const float* __restrict__ x, const float* __restrict__ g1, const float* __restrict__ b1,
    const unsigned short* __restrict__ qwtf, const float* __restrict__ qb,
    unsigned short* __restrict__ qkvb, unsigned short* __restrict__ vF)
{
    const int tid = threadIdx.x, wave = tid >> 6, lane = tid & 63;
    const int l15 = lane & 15, g4 = lane >> 4;
    const int row0 = blockIdx.x * 64 + wave * 16;

    s8v ha[3];
    {
        const int orig = wtok_to_orig(row0 + l15);
        ln_frag(x + (size_t)orig * CC, g1, b1, g4, ha);
    }

    #pragma unroll
    for (int ck = 0; ck < 3; ++ck) {
        fx4 acc[6];
        #pragma unroll
        for (int nt = 0; nt < 6; ++nt) acc[nt] = (fx4){0.f,0.f,0.f,0.f};
        #pragma unroll
        for (int ks = 0; ks < 3; ++ks) {
            #pragma unroll
            for (int nt = 0; nt < 6; ++nt) {
                s8v b = *reinterpret_cast<const s8v*>(
                    &qwtf[(((ck * 6 + nt) * 3 + ks) * 64 + lane) * 8]);
                acc[nt] = MFMA16(ha[ks], b, acc[nt]);
            }
        }
        const int rowb = row0 + g4 * 4;
        if (ck < 2) {                       // Q (pre-scaled) and K -> qkvb
            const float qmul = (ck == 0) ? QKSCALE : 1.f;
            #pragma unroll
            for (int nt = 0; nt < 6; ++nt) {
                const int col = ck * 96 + nt * 16 + l15;
                const float qbc = qb[col] * qmul;
                #pragma unroll
                for (int r = 0; r < 4; ++r)
                    qkvb[(size_t)(rowb + r) * 288 + col] = f2bf(acc[nt][r] + qbc);
            }
        } else {                            // V -> vF fragment order
            #pragma unroll
            for (int nt = 0; nt < 6; ++nt) {
                const int dg  = nt * 16 + l15;      // 0..95
                const float qbc = qb[192 + dg];
                const int hh  = dg >> 5, dd = dg & 31;
                const int ntp = dd >> 4, llo = dd & 15;
                #pragma unroll
                for (int r = 0; r < 4; ++r) {
                    const int tok = rowb + r;
                    const int win = tok / 49, p = tok - win * 49;
                    const int ksp = p >> 5, rem = p & 31;
                    const int g4p = rem >> 3, jj = rem & 7;
                    vF[((size_t)(win * 3 + hh) * 4 + ksp * 2 + ntp) * 512 +
                       (g4p * 16 + llo) * 8 + jj] = f2bf(acc[nt][r] + qbc);
                }
            }
        }
    }
}

// ---------- K2: MFMA attention; V and bias+mask pre-arranged in frag layout ----------
extern "C" __global__ void __launch_bounds__(64, 2) k2_attn(
    unsigned short* __restrict__ qkvb, const unsigned short* __restrict__ vF,
    const float* __restrict__ bmf)
{
    __shared__ unsigned short P[64][72];   // 9216 B
    const int lane = threadIdx.x;
    const int l15 = lane & 15, g4 = lane >> 4;
    const int task = blockIdx.x;
    const int win = task / 3, h = task - win * 3;
    const int g0  = win * NTK;
    const int w   = win & 63;
    const int cls = (((w >> 3) == 7) ? 2 : 0) + (((w & 7) == 7) ? 1 : 0);
    const float* BMF = bmf + (size_t)(cls * 3 + h) * 4096;
    const unsigned short* vFwh = vF + (size_t)(win * 3 + h) * 2048;

    s8v aq[4], bk[4];
    #pragma unroll
    for (int mt = 0; mt < 4; ++mt) {
        int tok = mt * 16 + l15; if (tok > 48) tok = 48;
        const unsigned short* qp = &qkvb[(size_t)(g0 + tok) * 288 + h * HDM + g4 * 8];
        aq[mt] = *reinterpret_cast<const s8v*>(qp);        // Q (pre-scaled)
        bk[mt] = *reinterpret_cast<const s8v*>(qp + 96);   // K
    }

    fx4 sc[4][4];
    #pragma unroll
    for (int mt = 0; mt < 4; ++mt)
        #pragma unroll
        for (int nt = 0; nt < 4; ++nt)
            sc[mt][nt] = MFMA16(aq[mt], bk[nt], ((fx4){0.f,0.f,0.f,0.f}));

    #pragma unroll
    for (int mt = 0; mt < 4; ++mt) {
        fx4 bmv[4];
        #pragma unroll
        for (int nt = 0; nt < 4; ++nt)
            bmv[nt] = *reinterpret_cast<const fx4*>(&BMF[((mt * 4 + nt) << 8) + lane * 4]);
        #pragma unroll
        for (int r = 0; r < 4; ++r) {
            float rs1 = 0.f;
            #pragma unroll
            for (int nt = 0; nt < 4; ++nt) {
                const int n = nt * 16 + l15;
                float s = sc[mt][nt][r] + bmv[nt][r];
                float e = (n < NTK) ? __expf(s) : 0.f;
                sc[mt][nt][r] = e;
                rs1 += e;
            }
            rs1 += __shfl_xor(rs1, 1); rs1 += __shfl_xor(rs1, 2);
            rs1 += __shfl_xor(rs1, 4); rs1 += __shfl_xor(rs1, 8);
            const float iv1 = 1.f / rs1;
            float rs2 = 0.f;
            #pragma unroll
            for (int nt = 0; nt < 4; ++nt) {
                const int n = nt * 16 + l15;
                float e2 = (n < NTK) ? __expf(sc[mt][nt][r] * iv1) : 0.f;
                sc[mt][nt][r] = e2;
                rs2 += e2;
            }
            rs2 += __shfl_xor(rs2, 1); rs2 += __shfl_xor(rs2, 2);
            rs2 += __shfl_xor(rs2, 4); rs2 += __shfl_xor(rs2, 8);
            const float iv2 = 1.f / rs2;
            const int m = mt * 16 + g4 * 4 + r;
            #pragma unroll
            for (int nt = 0; nt < 4; ++nt)
                P[m][nt * 16 + l15] = f2bf(sc[mt][nt][r] * iv2);
        }
    }
    __syncthreads();

    fx4 oc[4][2];
    #pragma unroll
    for (int mt = 0; mt < 4; ++mt) { oc[mt][0] = (fx4){0.f,0.f,0.f,0.f}; oc[mt][1] = (fx4){0.f,0.f,0.f,0.f}; }
    #pragma unroll
    for (int ks = 0; ks < 2; ++ks) {
        s8v vb[2];
        #pragma unroll
        for (int nt = 0; nt < 2; ++nt)
            vb[nt] = *reinterpret_cast<const s8v*>(&vFwh[((ks * 2 + nt) * 64 + lane) * 8]);
        #pragma unroll
        for (int mt = 0; mt < 4; ++mt) {
            s8v pa = *reinterpret_cast<const s8v*>(&P[mt * 16 + l15][ks * 32 + g4 * 8]);
            oc[mt][0] = MFMA16(pa, vb[0], oc[mt][0]);
            oc[mt][1] = MFMA16(pa, vb[1], oc[mt][1]);
        }
    }
    #pragma unroll
    for (int mt = 0; mt < 4; ++mt) {
        #pragma unroll
        for (int r = 0; r < 4; ++r) {
            const int m = mt * 16 + g4 * 4 + r;
            if (m < NTK) {
                qkvb[(size_t)(g0 + m) * 288 + h * HDM + l15]      = f2bf(oc[mt][0][r]);
                qkvb[(size_t)(g0 + m) * 288 + h * HDM + 16 + l15] = f2bf(oc[mt][1][r]);
            }
        }
    }
}

// ---------- K2b: barrier-free proj GEMM + residual + un-shift scatter ----------
extern "C" __global__ void __launch_bounds__(256, 3) k2b_proj(
    const unsigned short* __restrict__ qkvb, const unsigned short* __restrict__ pwtf,
    const float* __restrict__ pb, const float* __restrict__ x, float* __restrict__ out)
{
    const int tid = threadIdx.x, wave = tid >> 6, lane = tid & 63;
    const int l15 = lane & 15, g4 = lane >> 4;
    const int row0 = blockIdx.x * 64 + wave * 16;

    const unsigned short* arow = qkvb + (size_t)(row0 + l15) * 288 + g4 * 8;
    s8v a[3];
    a[0] = *reinterpret_cast<const s8v*>(arow);
    a[1] = *reinterpret_cast<const s8v*>(arow + 32);
    a[2] = *reinterpret_cast<const s8v*>(arow + 64);

    fx4 acc[6];
    #pragma unroll
    for (int nt = 0; nt < 6; ++nt) acc[nt] = (fx4){0.f,0.f,0.f,0.f};
    #pragma unroll
    for (int ks = 0; ks < 3; ++ks) {
        #pragma unroll
        for (int nt = 0; nt < 6; ++nt) {
            s8v b = *reinterpret_cast<const s8v*>(&pwtf[((nt * 3 + ks) * 64 + lane) * 8]);
            acc[nt] = MFMA16(a[ks], b, acc[nt]);
        }
    }
    int orig[4];
    #pragma unroll
    for (int r = 0; r < 4; ++r)
        orig[r] = wtok_to_orig(row0 + g4 * 4 + r);
    #pragma unroll
    for (int nt = 0; nt < 6; ++nt) {
        const int col = nt * 16 + l15;
        const float pbc = pb[col];
        #pragma unroll
        for (int r = 0; r < 4; ++r) {
            const size_t idx = (size_t)orig[r] * CC + col;
            out[idx] = acc[nt][r] + pbc + x[idx];
        }
    }
}

// ---------- K3: barrier-free MLP (R15 form, unroll 1 — full unroll regressed) ----------
#define LDA 72
extern "C" __global__ void __launch_bounds__(256, 3) k3_mlp(
    float* __restrict__ xio, const float* __restrict__ g2, const float* __restrict__ b2,
    const unsigned short* __restrict__ w1f, const float* __restrict__ bf1,
    const unsigned short* __restrict__ w2f, const float* __restrict__ bf2)
{
    __shared__ unsigned short Ac[64 * LDA];    // 9216 B, wave-private rows
    const int tid = threadIdx.x, wave = tid >> 6, lane = tid & 63;
    const int l15 = lane & 15, g4 = lane >> 4;
    const int row0 = blockIdx.x * 64 + wave * 16;

    s8v ha[3];
    ln_frag(xio + (size_t)(row0 + l15) * CC, g2, b2, g4, ha);

    fx4 oacc[6];
    #pragma unroll
    for (int nt = 0; nt < 6; ++nt) oacc[nt] = (fx4){0.f,0.f,0.f,0.f};

    #pragma unroll 1
    for (int ck = 0; ck < 6; ++ck) {
        fx4 a1[4];
        #pragma unroll
        for (int nt = 0; nt < 4; ++nt) a1[nt] = (fx4){0.f,0.f,0.f,0.f};
        #pragma unroll
        for (int ks = 0; ks < 3; ++ks) {
            #pragma unroll
            for (int nt = 0; nt < 4; ++nt) {
                s8v b = *reinterpret_cast<const s8v*>(
                    &w1f[(((ck * 4 + nt) * 3 + ks) * 64 + lane) * 8]);
                a1[nt] = MFMA16(ha[ks], b, a1[nt]);
            }
        }
        #pragma unroll
        for (int nt = 0; nt < 4; ++nt) {
            const float bb = bf1[ck * 64 + nt * 16 + l15];
            #pragma unroll
            for (int r = 0; r < 4; ++r) {
                float v0 = a1[nt][r] + bb;
                Ac[(wave*16 + g4*4 + r) * LDA + nt*16 + l15] = f2bf(gelu_t(gelu_t(v0)));
            }
        }
        #pragma unroll
        for (int ks = 0; ks < 2; ++ks) {
            s8v a = *reinterpret_cast<const s8v*>(&Ac[(wave*16 + l15)*LDA + ks*32 + g4*8]);
            #pragma unroll
            for (int nt = 0; nt < 6; ++nt) {
                s8v b = *reinterpret_cast<const s8v*>(
                    &w2f[(((ck * 6 + nt) * 2 + ks) * 64 + lane) * 8]);
                oacc[nt] = MFMA16(a, b, oacc[nt]);
            }
        }
    }

    const int rowb = row0 + g4 * 4;
    #pragma unroll
    for (int nt = 0; nt < 6; ++nt) {
        const int col = nt * 16 + l15;
        const float bb = bf2[col];
        #pragma unroll
        for (int r = 0; r < 4; ++r) {
            const size_t idx = (size_t)(rowb + r) * CC + col;
            xio[idx] = xio[idx] + oacc[nt][r] + bb;
        }
    }
}

extern "C" void kernel_launch(void* const* d_in, const int* in_sizes, int n_in,
                              void* d_out, int out_size, void* d_ws, size_t ws_size,
                              hipStream_t stream)
{
    const float* x    = (const float*)d_in[0];
    const float* n1g  = (const float*)d_in[1];
    const float* n1b  = (const float*)d_in[2];
    const float* qw   = (const float*)d_in[3];
    const float* qb   = (const float*)d_in[4];
    const float* btab = (const float*)d_in[5];
    const float* pw   = (const float*)d_in[6];
    const float* pb   = (const float*)d_in[7];
    const float* n2g  = (const float*)d_in[8];
    const float* n2b  = (const float*)d_in[9];
    const float* w1   = (const float*)d_in[10];
    const float* bf1  = (const float*)d_in[11];
    const float* w2   = (const float*)d_in[12];
    const float* bf2  = (const float*)d_in[13];
    float* out = (float*)d_out;

    unsigned short* qkvb = (unsigned short*)d_ws;                 // TOT*288 bf16 = 57.8 MB
    unsigned short* wbf  = qkvb + (size_t)TOT * 288;
    unsigned short* qwtf = wbf;                                   // 27648 frag-linear
    unsigned short* pwtf = qwtf + 27648;                          // 9216 frag-linear
    unsigned short* w1f  = pwtf + 9216;                           // 36864 frag-linear
    unsigned short* w2f  = w1f + 36864;                           // 36864 frag-linear
    float* bmf = (float*)(wbf + 110592);                          // 49152 fp32 (D-frag)
    unsigned short* vF = wbf + 110592 + 98304;                    // 6144*2048 bf16 = 25 MB

    p0_prep <<<624, 256, 0, stream>>>(qw, pw, w1, w2, btab, wbf);
    k1_qkv  <<<TOT/64, 256, 0, stream>>>(x, n1g, n1b, qwtf, qb, qkvb, vF);
    k2_attn <<<BB*NWIN*NHD, 64, 0, stream>>>(qkvb, vF, bmf);
    k2b_proj<<<TOT/64, 256, 0, stream>>>(qkvb, pwtf, pb, x, out);
    k3_mlp  <<<TOT/64, 256, 0, stream>>>(out, n2g, n2b, w1f, bf1, w2f, bf2);
}

// Round 20
// 144.586 us; speedup vs baseline: 1.2005x; 1.0008x over previous
//
#include <hip/hip_runtime.h>
#include <math.h>

#define BB   32
#define HH   56
#define WWI  56
#define CC   96
#define NHD  3
#define WSZ  7
#define SHF  3
#define NTK  49
#define NWIN 64
#define HDM  32
#define TOT  (BB*HH*WWI)               // 100352
#define QKSCALE 0.17677669529663687f
#define LEPS 1e-3f

typedef __attribute__((ext_vector_type(8))) short s8v;   // 8 bf16 (4 VGPRs)
typedef __attribute__((ext_vector_type(4))) float fx4;   // 4 fp32
typedef unsigned long long ull_t;

#define MFMA16(a,b,c) __builtin_amdgcn_mfma_f32_16x16x32_bf16((a),(b),(c),0,0,0)

__device__ __forceinline__ unsigned short f2bf(float f) {
    union { float f; unsigned u; } v; v.f = f;
    unsigned r = v.u + 0x7FFFu + ((v.u >> 16) & 1u);
    return (unsigned short)(r >> 16);
}

// sigmoid-form gelu (tanh approx): |err vs exact| <~2e-3, ~8 VALU ops vs ~28 for erff
__device__ __forceinline__ float gelu_t(float x) {
    float x3 = x * x * x;
    float z = -1.5957691216f * fmaf(0.044715f, x3, x);
    return x * __builtin_amdgcn_rcpf(1.f + __expf(z));
}

// windowed token id -> original flat token id (roll(-3,-3) + window partition)
__device__ __forceinline__ int wtok_to_orig(int wt) {
    int win = wt / NTK;
    int p   = wt - win * NTK;
    int b   = win >> 6;
    int w   = win & 63;
    int wi = w >> 3, wj = w & 7;
    int pi = p / WSZ, pj = p - pi * WSZ;
    int r = wi * WSZ + pi + SHF; if (r >= HH) r -= HH;
    int c = wj * WSZ + pj + SHF; if (c >= WWI) c -= WWI;
    return b * (HH * WWI) + r * WWI + c;
}

// LayerNorm in MFMA-A-fragment layout (reduction via shfl_xor 16/32)
__device__ __forceinline__ void ln_frag(const float* __restrict__ row,
                                        const float* __restrict__ gg,
                                        const float* __restrict__ bb,
                                        int g4, s8v ha[3])
{
    float h[24];
    #pragma unroll
    for (int ks = 0; ks < 3; ++ks) {
        fx4 v0 = *reinterpret_cast<const fx4*>(row + ks * 32 + g4 * 8);
        fx4 v1 = *reinterpret_cast<const fx4*>(row + ks * 32 + g4 * 8 + 4);
        h[ks*8+0]=v0.x; h[ks*8+1]=v0.y; h[ks*8+2]=v0.z; h[ks*8+3]=v0.w;
        h[ks*8+4]=v1.x; h[ks*8+5]=v1.y; h[ks*8+6]=v1.z; h[ks*8+7]=v1.w;
    }
    float s = 0.f, s2 = 0.f;
    #pragma unroll
    for (int j = 0; j < 24; ++j) { s += h[j]; s2 = fmaf(h[j], h[j], s2); }
    s  += __shfl_xor(s, 16);  s  += __shfl_xor(s, 32);
    s2 += __shfl_xor(s2, 16); s2 += __shfl_xor(s2, 32);
    const float mu = s * (1.f/CC);
    const float rs = rsqrtf(s2 * (1.f/CC) - mu * mu + LEPS);
    #pragma unroll
    for (int ks = 0; ks < 3; ++ks) {
        union { s8v v; unsigned short u[8]; } p;
        #pragma unroll
        for (int j = 0; j < 8; ++j) {
            int c = ks * 32 + g4 * 8 + j;
            p.u[j] = f2bf((h[ks*8+j] - mu) * rs * gg[c] + bb[c]);
        }
        ha[ks] = p.v;
    }
}

// ---------- P0: weights frag-linearized + BM in D-fragment layout ----------
extern "C" __global__ void p0_prep(const float* __restrict__ qw, const float* __restrict__ pw,
                                   const float* __restrict__ w1, const float* __restrict__ w2,
                                   const float* __restrict__ btab,
                                   unsigned short* __restrict__ wsw)
{
    int i = blockIdx.x * 256 + threadIdx.x;
    if (i < 27648) {                       // qwtf frag-linear
        int e = i & 7, f = i >> 3;
        int lane = f & 63, fid = f >> 6;   // fid 0..53
        int ks = fid % 3, t = fid / 3;
        int nt = t % 6, ck = t / 6;
        int n = ck * 96 + nt * 16 + (lane & 15);
        int k = ks * 32 + (lane >> 4) * 8 + e;
        float v = qw[k * 288 + n];
        if (n < 96) v *= QKSCALE;
        wsw[i] = f2bf(v);
    } else if (i < 36864) {                // pwtf frag-linear
        int j = i - 27648;
        int e = j & 7, f = j >> 3;
        int lane = f & 63, fid = f >> 6;   // fid 0..17
        int ks = fid % 3, nt = fid / 3;
        int n = nt * 16 + (lane & 15);
        int k = ks * 32 + (lane >> 4) * 8 + e;
        wsw[i] = f2bf(pw[k * 96 + n]);
    } else if (i < 73728) {                // w1f frag-linear
        int j = i - 36864;
        int e = j & 7, f = j >> 3;
        int lane = f & 63, fid = f >> 6;
        int ks = fid % 3, t = fid / 3;
        int nt = t & 3, ck = t >> 2;
        int n = ck * 64 + nt * 16 + (lane & 15);
        int k = ks * 32 + (lane >> 4) * 8 + e;
        wsw[i] = f2bf(w1[k * 384 + n]);
    } else if (i < 110592) {               // w2f frag-linear
        int j = i - 73728;
        int e = j & 7, f = j >> 3;
        int lane = f & 63, fid = f >> 6;
        int ks = fid & 1, t = fid >> 1;
        int nt = t % 6, ck = t / 6;
        int n = nt * 16 + (lane & 15);
        int k = ck * 64 + ks * 32 + (lane >> 4) * 8 + e;
        wsw[i] = f2bf(w2[k * 96 + n]);
    } else if (i < 159744) {               // bmf: BM in D-frag layout (fp32)
        float* bmf = (float*)(wsw + 110592);
        int j = i - 110592;                // 0..49151
        int r = j & 3, lane = (j >> 2) & 63;
        int fid = j >> 8;                  // 0..191
        int mtnt = fid & 15, t = fid >> 4; // t 0..11
        int mt = mtnt >> 2, nt = mtnt & 3;
        int hd = t % 3, cls = t / 3;
        int m = mt * 16 + (lane >> 4) * 4 + r; if (m > 48) m = 48;
        int n = nt * 16 + (lane & 15);
        float val = 0.f;
        if (n < 49) {
            int it = m / 7, jt = m - it * 7;
            int iu = n / 7, ju = n - iu * 7;
            int li  = (cls & 2) ? (it < 4 ? 1 : 2) : 0;
            int lj  = (cls & 1) ? (jt < 4 ? 1 : 2) : 0;
            int lui = (cls & 2) ? (iu < 4 ? 1 : 2) : 0;
            int luj = (cls & 1) ? (ju < 4 ? 1 : 2) : 0;
            int bidx = (jt - ju + 6) * 13 + (it - iu + 6);
            val = btab[bidx * 3 + hd] + ((li*3+lj) == (lui*3+luj) ? 0.f : -100.f);
        }
        bmf[j] = val;
    }
}

// ---------- K1: barrier-free gather + LN1(frag) + QKV MFMA -> qkvb bf16 (R18 form) ----------
// ck loop fully unrolled (R18: ~+9us via cross-ck load pipelining). No vF scatter
// (R19: fragment-order V scatter cost ~11us on the producer side — reverted).
extern "C" __global__ void __launch_bounds__(256, 3) k1_qkv(
    const float* __restrict__ x, const float* __restrict__ g1, const float* __restrict__ b1,
    const unsigned short* __restrict__ qwtf, const float* __restrict__ qb,
    unsigned short* __restrict__ qkvb)
{
    const int tid = threadIdx.x, wave = tid >> 6, lane = tid & 63;
    const int l15 = lane & 15, g4 = lane >> 4;
    const int row0 = blockIdx.x * 64 + wave * 16;

    s8v ha[3];
    {
        const int orig = wtok_to_orig(row0 + l15);
        ln_frag(x + (size_t)orig * CC, g1, b1, g4, ha);
    }

    #pragma unroll
    for (int ck = 0; ck < 3; ++ck) {
        fx4 acc[6];
        #pragma unroll
        for (int nt = 0; nt < 6; ++nt) acc[nt] = (fx4){0.f,0.f,0.f,0.f};
        #pragma unroll
        for (int ks = 0; ks < 3; ++ks) {
            #pragma unroll
            for (int nt = 0; nt < 6; ++nt) {
                s8v b = *reinterpret_cast<const s8v*>(
                    &qwtf[(((ck * 6 + nt) * 3 + ks) * 64 + lane) * 8]);
                acc[nt] = MFMA16(ha[ks], b, acc[nt]);
            }
        }
        const int rowb = row0 + g4 * 4;
        const float qmul = (ck == 0) ? QKSCALE : 1.f;   // qb scale matches scaled qwtf
        #pragma unroll
        for (int nt = 0; nt < 6; ++nt) {
            const int col = ck * 96 + nt * 16 + l15;
            const float qbc = qb[col] * qmul;
            #pragma unroll
            for (int r = 0; r < 4; ++r)
                qkvb[(size_t)(rowb + r) * 288 + col] = f2bf(acc[nt][r] + qbc);
        }
    }
}

// ---------- K2: MFMA attention; V scalar-gather (R15), bias+mask via bmf ----------
extern "C" __global__ void __launch_bounds__(64, 2) k2_attn(
    unsigned short* __restrict__ qkvb, const float* __restrict__ bmf)
{
    __shared__ unsigned short P[64][72];   // 9216 B
    const int lane = threadIdx.x;
    const int l15 = lane & 15, g4 = lane >> 4;
    const int task = blockIdx.x;
    const int win = task / 3, h = task - win * 3;
    const int g0  = win * NTK;
    const int w   = win & 63;
    const int cls = (((w >> 3) == 7) ? 2 : 0) + (((w & 7) == 7) ? 1 : 0);
    const float* BMF = bmf + (size_t)(cls * 3 + h) * 4096;

    s8v aq[4], bk[4];
    #pragma unroll
    for (int mt = 0; mt < 4; ++mt) {
        int tok = mt * 16 + l15; if (tok > 48) tok = 48;
        const unsigned short* qp = &qkvb[(size_t)(g0 + tok) * 288 + h * HDM + g4 * 8];
        aq[mt] = *reinterpret_cast<const s8v*>(qp);        // Q (pre-scaled)
        bk[mt] = *reinterpret_cast<const s8v*>(qp + 96);   // K
    }

    fx4 sc[4][4];
    #pragma unroll
    for (int mt = 0; mt < 4; ++mt)
        #pragma unroll
        for (int nt = 0; nt < 4; ++nt)
            sc[mt][nt] = MFMA16(aq[mt], bk[nt], ((fx4){0.f,0.f,0.f,0.f}));

    #pragma unroll
    for (int mt = 0; mt < 4; ++mt) {
        fx4 bmv[4];
        #pragma unroll
        for (int nt = 0; nt < 4; ++nt)
            bmv[nt] = *reinterpret_cast<const fx4*>(&BMF[((mt * 4 + nt) << 8) + lane * 4]);
        #pragma unroll
        for (int r = 0; r < 4; ++r) {
            float rs1 = 0.f;
            #pragma unroll
            for (int nt = 0; nt < 4; ++nt) {
                const int n = nt * 16 + l15;
                float s = sc[mt][nt][r] + bmv[nt][r];
                float e = (n < NTK) ? __expf(s) : 0.f;
                sc[mt][nt][r] = e;
                rs1 += e;
            }
            rs1 += __shfl_xor(rs1, 1); rs1 += __shfl_xor(rs1, 2);
            rs1 += __shfl_xor(rs1, 4); rs1 += __shfl_xor(rs1, 8);
            const float iv1 = 1.f / rs1;
            float rs2 = 0.f;
            #pragma unroll
            for (int nt = 0; nt < 4; ++nt) {
                const int n = nt * 16 + l15;
                float e2 = (n < NTK) ? __expf(sc[mt][nt][r] * iv1) : 0.f;
                sc[mt][nt][r] = e2;
                rs2 += e2;
            }
            rs2 += __shfl_xor(rs2, 1); rs2 += __shfl_xor(rs2, 2);
            rs2 += __shfl_xor(rs2, 4); rs2 += __shfl_xor(rs2, 8);
            const float iv2 = 1.f / rs2;
            const int m = mt * 16 + g4 * 4 + r;
            #pragma unroll
            for (int nt = 0; nt < 4; ++nt)
                P[m][nt * 16 + l15] = f2bf(sc[mt][nt][r] * iv2);
        }
    }
    __syncthreads();

    fx4 oc[4][2];
    #pragma unroll
    for (int mt = 0; mt < 4; ++mt) { oc[mt][0] = (fx4){0.f,0.f,0.f,0.f}; oc[mt][1] = (fx4){0.f,0.f,0.f,0.f}; }
    #pragma unroll
    for (int ks = 0; ks < 2; ++ks) {
        s8v vb[2];
        #pragma unroll
        for (int nt = 0; nt < 2; ++nt) {
            union { s8v v; unsigned short u[8]; } pv;
            #pragma unroll
            for (int j = 0; j < 8; ++j) {
                int tok = ks * 32 + g4 * 8 + j; if (tok > 48) tok = 48;
                pv.u[j] = qkvb[(size_t)(g0 + tok) * 288 + 192 + h * HDM + nt * 16 + l15];
            }
            vb[nt] = pv.v;
        }
        #pragma unroll
        for (int mt = 0; mt < 4; ++mt) {
            s8v pa = *reinterpret_cast<const s8v*>(&P[mt * 16 + l15][ks * 32 + g4 * 8]);
            oc[mt][0] = MFMA16(pa, vb[0], oc[mt][0]);
            oc[mt][1] = MFMA16(pa, vb[1], oc[mt][1]);
        }
    }
    #pragma unroll
    for (int mt = 0; mt < 4; ++mt) {
        #pragma unroll
        for (int r = 0; r < 4; ++r) {
            const int m = mt * 16 + g4 * 4 + r;
            if (m < NTK) {
                qkvb[(size_t)(g0 + m) * 288 + h * HDM + l15]      = f2bf(oc[mt][0][r]);
                qkvb[(size_t)(g0 + m) * 288 + h * HDM + 16 + l15] = f2bf(oc[mt][1][r]);
            }
        }
    }
}

// ---------- K2b: barrier-free proj GEMM + residual + un-shift scatter ----------
extern "C" __global__ void __launch_bounds__(256, 3) k2b_proj(
    const unsigned short* __restrict__ qkvb, const unsigned short* __restrict__ pwtf,
    const float* __restrict__ pb, const float* __restrict__ x, float* __restrict__ out)
{
    const int tid = threadIdx.x, wave = tid >> 6, lane = tid & 63;
    const int l15 = lane & 15, g4 = lane >> 4;
    const int row0 = blockIdx.x * 64 + wave * 16;

    const unsigned short* arow = qkvb + (size_t)(row0 + l15) * 288 + g4 * 8;
    s8v a[3];
    a[0] = *reinterpret_cast<const s8v*>(arow);
    a[1] = *reinterpret_cast<const s8v*>(arow + 32);
    a[2] = *reinterpret_cast<const s8v*>(arow + 64);

    fx4 acc[6];
    #pragma unroll
    for (int nt = 0; nt < 6; ++nt) acc[nt] = (fx4){0.f,0.f,0.f,0.f};
    #pragma unroll
    for (int ks = 0; ks < 3; ++ks) {
        #pragma unroll
        for (int nt = 0; nt < 6; ++nt) {
            s8v b = *reinterpret_cast<const s8v*>(&pwtf[((nt * 3 + ks) * 64 + lane) * 8]);
            acc[nt] = MFMA16(a[ks], b, acc[nt]);
        }
    }
    int orig[4];
    #pragma unroll
    for (int r = 0; r < 4; ++r)
        orig[r] = wtok_to_orig(row0 + g4 * 4 + r);
    #pragma unroll
    for (int nt = 0; nt < 6; ++nt) {
        const int col = nt * 16 + l15;
        const float pbc = pb[col];
        #pragma unroll
        for (int r = 0; r < 4; ++r) {
            const size_t idx = (size_t)orig[r] * CC + col;
            out[idx] = acc[nt][r] + pbc + x[idx];
        }
    }
}

// ---------- K3: barrier-free MLP (R15 form, unroll 1 — full unroll regressed) ----------
#define LDA 72
extern "C" __global__ void __launch_bounds__(256, 3) k3_mlp(
    float* __restrict__ xio, const float* __restrict__ g2, const float* __restrict__ b2,
    const unsigned short* __restrict__ w1f, const float* __restrict__ bf1,
    const unsigned short* __restrict__ w2f, const float* __restrict__ bf2)
{
    __shared__ unsigned short Ac[64 * LDA];    // 9216 B, wave-private rows
    const int tid = threadIdx.x, wave = tid >> 6, lane = tid & 63;
    const int l15 = lane & 15, g4 = lane >> 4;
    const int row0 = blockIdx.x * 64 + wave * 16;

    s8v ha[3];
    ln_frag(xio + (size_t)(row0 + l15) * CC, g2, b2, g4, ha);

    fx4 oacc[6];
    #pragma unroll
    for (int nt = 0; nt < 6; ++nt) oacc[nt] = (fx4){0.f,0.f,0.f,0.f};

    #pragma unroll 1
    for (int ck = 0; ck < 6; ++ck) {
        fx4 a1[4];
        #pragma unroll
        for (int nt = 0; nt < 4; ++nt) a1[nt] = (fx4){0.f,0.f,0.f,0.f};
        #pragma unroll
        for (int ks = 0; ks < 3; ++ks) {
            #pragma unroll
            for (int nt = 0; nt < 4; ++nt) {
                s8v b = *reinterpret_cast<const s8v*>(
                    &w1f[(((ck * 4 + nt) * 3 + ks) * 64 + lane) * 8]);
                a1[nt] = MFMA16(ha[ks], b, a1[nt]);
            }
        }
        #pragma unroll
        for (int nt = 0; nt < 4; ++nt) {
            const float bb = bf1[ck * 64 + nt * 16 + l15];
            #pragma unroll
            for (int r = 0; r < 4; ++r) {
                float v0 = a1[nt][r] + bb;
                Ac[(wave*16 + g4*4 + r) * LDA + nt*16 + l15] = f2bf(gelu_t(gelu_t(v0)));
            }
        }
        #pragma unroll
        for (int ks = 0; ks < 2; ++ks) {
            s8v a = *reinterpret_cast<const s8v*>(&Ac[(wave*16 + l15)*LDA + ks*32 + g4*8]);
            #pragma unroll
            for (int nt = 0; nt < 6; ++nt) {
                s8v b = *reinterpret_cast<const s8v*>(
                    &w2f[(((ck * 6 + nt) * 2 + ks) * 64 + lane) * 8]);
                oacc[nt] = MFMA16(a, b, oacc[nt]);
            }
        }
    }

    const int rowb = row0 + g4 * 4;
    #pragma unroll
    for (int nt = 0; nt < 6; ++nt) {
        const int col = nt * 16 + l15;
        const float bb = bf2[col];
        #pragma unroll
        for (int r = 0; r < 4; ++r) {
            const size_t idx = (size_t)(rowb + r) * CC + col;
            xio[idx] = xio[idx] + oacc[nt][r] + bb;
        }
    }
}

extern "C" void kernel_launch(void* const* d_in, const int* in_sizes, int n_in,
                              void* d_out, int out_size, void* d_ws, size_t ws_size,
                              hipStream_t stream)
{
    const float* x    = (const float*)d_in[0];
    const float* n1g  = (const float*)d_in[1];
    const float* n1b  = (const float*)d_in[2];
    const float* qw   = (const float*)d_in[3];
    const float* qb   = (const float*)d_in[4];
    const float* btab = (const float*)d_in[5];
    const float* pw   = (const float*)d_in[6];
    const float* pb   = (const float*)d_in[7];
    const float* n2g  = (const float*)d_in[8];
    const float* n2b  = (const float*)d_in[9];
    const float* w1   = (const float*)d_in[10];
    const float* bf1  = (const float*)d_in[11];
    const float* w2   = (const float*)d_in[12];
    const float* bf2  = (const float*)d_in[13];
    float* out = (float*)d_out;

    unsigned short* qkvb = (unsigned short*)d_ws;                 // TOT*288 bf16 = 57.8 MB
    unsigned short* wbf  = qkvb + (size_t)TOT * 288;
    unsigned short* qwtf = wbf;                                   // 27648 frag-linear
    unsigned short* pwtf = qwtf + 27648;                          // 9216 frag-linear
    unsigned short* w1f  = pwtf + 9216;                           // 36864 frag-linear
    unsigned short* w2f  = w1f + 36864;                           // 36864 frag-linear
    float* bmf = (float*)(wbf + 110592);                          // 49152 fp32 (D-frag)

    p0_prep <<<624, 256, 0, stream>>>(qw, pw, w1, w2, btab, wbf);
    k1_qkv  <<<TOT/64, 256, 0, stream>>>(x, n1g, n1b, qwtf, qb, qkvb);
    k2_attn <<<BB*NWIN*NHD, 64, 0, stream>>>(qkvb, bmf);
    k2b_proj<<<TOT/64, 256, 0, stream>>>(qkvb, pwtf, pb, x, out);
    k3_mlp  <<<TOT/64, 256, 0, stream>>>(out, n2g, n2b, w1f, bf1, w2f, bf2);
}

// Round 21
// 142.635 us; speedup vs baseline: 1.2170x; 1.0137x over previous
//
#include <hip/hip_runtime.h>
#include <math.h>

#define BB   32
#define HH   56
#define WWI  56
#define CC   96
#define NHD  3
#define WSZ  7
#define SHF  3
#define NTK  49
#define NWIN 64
#define HDM  32
#define TOT  (BB*HH*WWI)               // 100352
#define QKSCALE 0.17677669529663687f
#define LEPS 1e-3f

typedef __attribute__((ext_vector_type(8))) short s8v;   // 8 bf16 (4 VGPRs)
typedef __attribute__((ext_vector_type(4))) float fx4;   // 4 fp32
typedef unsigned long long ull_t;

#define MFMA16(a,b,c) __builtin_amdgcn_mfma_f32_16x16x32_bf16((a),(b),(c),0,0,0)

__device__ __forceinline__ unsigned short f2bf(float f) {
    union { float f; unsigned u; } v; v.f = f;
    unsigned r = v.u + 0x7FFFu + ((v.u >> 16) & 1u);
    return (unsigned short)(r >> 16);
}

// sigmoid-form gelu, op-minimized: z = x*fma(K2,x^2,K1) (no separate x^3),
// log2(e) folded into constants so hardware v_exp_f32 is fed directly.
// Same function as before to ~1ulp; 7 ops vs 9.
__device__ __forceinline__ float gelu_t(float x) {
    float x2 = x * x;
#if __has_builtin(__builtin_amdgcn_exp2f)
    float z = x * fmaf(-0.10294326f, x2, -2.3022082f);   // -log2(e)*1.59577*(1, .044715)
    float e = __builtin_amdgcn_exp2f(z);
#else
    float z = x * fmaf(-0.07135529f, x2, -1.5957691f);
    float e = __expf(z);
#endif
    return x * __builtin_amdgcn_rcpf(1.f + e);
}

// windowed token id -> original flat token id (roll(-3,-3) + window partition)
__device__ __forceinline__ int wtok_to_orig(int wt) {
    int win = wt / NTK;
    int p   = wt - win * NTK;
    int b   = win >> 6;
    int w   = win & 63;
    int wi = w >> 3, wj = w & 7;
    int pi = p / WSZ, pj = p - pi * WSZ;
    int r = wi * WSZ + pi + SHF; if (r >= HH) r -= HH;
    int c = wj * WSZ + pj + SHF; if (c >= WWI) c -= WWI;
    return b * (HH * WWI) + r * WWI + c;
}

// LayerNorm in MFMA-A-fragment layout (reduction via shfl_xor 16/32)
__device__ __forceinline__ void ln_frag(const float* __restrict__ row,
                                        const float* __restrict__ gg,
                                        const float* __restrict__ bb,
                                        int g4, s8v ha[3])
{
    float h[24];
    #pragma unroll
    for (int ks = 0; ks < 3; ++ks) {
        fx4 v0 = *reinterpret_cast<const fx4*>(row + ks * 32 + g4 * 8);
        fx4 v1 = *reinterpret_cast<const fx4*>(row + ks * 32 + g4 * 8 + 4);
        h[ks*8+0]=v0.x; h[ks*8+1]=v0.y; h[ks*8+2]=v0.z; h[ks*8+3]=v0.w;
        h[ks*8+4]=v1.x; h[ks*8+5]=v1.y; h[ks*8+6]=v1.z; h[ks*8+7]=v1.w;
    }
    float s = 0.f, s2 = 0.f;
    #pragma unroll
    for (int j = 0; j < 24; ++j) { s += h[j]; s2 = fmaf(h[j], h[j], s2); }
    s  += __shfl_xor(s, 16);  s  += __shfl_xor(s, 32);
    s2 += __shfl_xor(s2, 16); s2 += __shfl_xor(s2, 32);
    const float mu = s * (1.f/CC);
    const float rs = rsqrtf(s2 * (1.f/CC) - mu * mu + LEPS);
    #pragma unroll
    for (int ks = 0; ks < 3; ++ks) {
        union { s8v v; unsigned short u[8]; } p;
        #pragma unroll
        for (int j = 0; j < 8; ++j) {
            int c = ks * 32 + g4 * 8 + j;
            p.u[j] = f2bf((h[ks*8+j] - mu) * rs * gg[c] + bb[c]);
        }
        ha[ks] = p.v;
    }
}

// ---------- P0: weights frag-linearized + BM in D-fragment layout ----------
extern "C" __global__ void p0_prep(const float* __restrict__ qw, const float* __restrict__ pw,
                                   const float* __restrict__ w1, const float* __restrict__ w2,
                                   const float* __restrict__ btab,
                                   unsigned short* __restrict__ wsw)
{
    int i = blockIdx.x * 256 + threadIdx.x;
    if (i < 27648) {                       // qwtf frag-linear
        int e = i & 7, f = i >> 3;
        int lane = f & 63, fid = f >> 6;   // fid 0..53
        int ks = fid % 3, t = fid / 3;
        int nt = t % 6, ck = t / 6;
        int n = ck * 96 + nt * 16 + (lane & 15);
        int k = ks * 32 + (lane >> 4) * 8 + e;
        float v = qw[k * 288 + n];
        if (n < 96) v *= QKSCALE;
        wsw[i] = f2bf(v);
    } else if (i < 36864) {                // pwtf frag-linear
        int j = i - 27648;
        int e = j & 7, f = j >> 3;
        int lane = f & 63, fid = f >> 6;   // fid 0..17
        int ks = fid % 3, nt = fid / 3;
        int n = nt * 16 + (lane & 15);
        int k = ks * 32 + (lane >> 4) * 8 + e;
        wsw[i] = f2bf(pw[k * 96 + n]);
    } else if (i < 73728) {                // w1f frag-linear
        int j = i - 36864;
        int e = j & 7, f = j >> 3;
        int lane = f & 63, fid = f >> 6;
        int ks = fid % 3, t = fid / 3;
        int nt = t & 3, ck = t >> 2;
        int n = ck * 64 + nt * 16 + (lane & 15);
        int k = ks * 32 + (lane >> 4) * 8 + e;
        wsw[i] = f2bf(w1[k * 384 + n]);
    } else if (i < 110592) {               // w2f frag-linear
        int j = i - 73728;
        int e = j & 7, f = j >> 3;
        int lane = f & 63, fid = f >> 6;
        int ks = fid & 1, t = fid >> 1;
        int nt = t % 6, ck = t / 6;
        int n = nt * 16 + (lane & 15);
        int k = ck * 64 + ks * 32 + (lane >> 4) * 8 + e;
        wsw[i] = f2bf(w2[k * 96 + n]);
    } else if (i < 159744) {               // bmf: BM in D-frag layout (fp32)
        float* bmf = (float*)(wsw + 110592);
        int j = i - 110592;                // 0..49151
        int r = j & 3, lane = (j >> 2) & 63;
        int fid = j >> 8;                  // 0..191
        int mtnt = fid & 15, t = fid >> 4; // t 0..11
        int mt = mtnt >> 2, nt = mtnt & 3;
        int hd = t % 3, cls = t / 3;
        int m = mt * 16 + (lane >> 4) * 4 + r; if (m > 48) m = 48;
        int n = nt * 16 + (lane & 15);
        float val = 0.f;
        if (n < 49) {
            int it = m / 7, jt = m - it * 7;
            int iu = n / 7, ju = n - iu * 7;
            int li  = (cls & 2) ? (it < 4 ? 1 : 2) : 0;
            int lj  = (cls & 1) ? (jt < 4 ? 1 : 2) : 0;
            int lui = (cls & 2) ? (iu < 4 ? 1 : 2) : 0;
            int luj = (cls & 1) ? (ju < 4 ? 1 : 2) : 0;
            int bidx = (jt - ju + 6) * 13 + (it - iu + 6);
            val = btab[bidx * 3 + hd] + ((li*3+lj) == (lui*3+luj) ? 0.f : -100.f);
        }
        bmf[j] = val;
    }
}

// ---------- K1: barrier-free gather + LN1(frag) + QKV MFMA -> qkvb bf16 ----------
extern "C" __global__ void __launch_bounds__(256, 3) k1_qkv(
    const float* __restrict__ x, const float* __restrict__ g1, const float* __restrict__ b1,
    const unsigned short* __restrict__ qwtf, const float* __restrict__ qb,
    unsigned short* __restrict__ qkvb)
{
    const int tid = threadIdx.x, wave = tid >> 6, lane = tid & 63;
    const int l15 = lane & 15, g4 = lane >> 4;
    const int row0 = blockIdx.x * 64 + wave * 16;

    s8v ha[3];
    {
        const int orig = wtok_to_orig(row0 + l15);
        ln_frag(x + (size_t)orig * CC, g1, b1, g4, ha);
    }

    #pragma unroll
    for (int ck = 0; ck < 3; ++ck) {
        fx4 acc[6];
        #pragma unroll
        for (int nt = 0; nt < 6; ++nt) acc[nt] = (fx4){0.f,0.f,0.f,0.f};
        #pragma unroll
        for (int ks = 0; ks < 3; ++ks) {
            #pragma unroll
            for (int nt = 0; nt < 6; ++nt) {
                s8v b = *reinterpret_cast<const s8v*>(
                    &qwtf[(((ck * 6 + nt) * 3 + ks) * 64 + lane) * 8]);
                acc[nt] = MFMA16(ha[ks], b, acc[nt]);
            }
        }
        const int rowb = row0 + g4 * 4;
        const float qmul = (ck == 0) ? QKSCALE : 1.f;   // qb scale matches scaled qwtf
        #pragma unroll
        for (int nt = 0; nt < 6; ++nt) {
            const int col = ck * 96 + nt * 16 + l15;
            const float qbc = qb[col] * qmul;
            #pragma unroll
            for (int r = 0; r < 4; ++r)
                qkvb[(size_t)(rowb + r) * 288 + col] = f2bf(acc[nt][r] + qbc);
        }
    }
}

// ---------- K2: MFMA attention; V scalar-gather, bias+mask via bmf; (64,3) ----------
extern "C" __global__ void __launch_bounds__(64, 3) k2_attn(
    unsigned short* __restrict__ qkvb, const float* __restrict__ bmf)
{
    __shared__ unsigned short P[64][72];   // 9216 B
    const int lane = threadIdx.x;
    const int l15 = lane & 15, g4 = lane >> 4;
    const int task = blockIdx.x;
    const int win = task / 3, h = task - win * 3;
    const int g0  = win * NTK;
    const int w   = win & 63;
    const int cls = (((w >> 3) == 7) ? 2 : 0) + (((w & 7) == 7) ? 1 : 0);
    const float* BMF = bmf + (size_t)(cls * 3 + h) * 4096;

    s8v aq[4], bk[4];
    #pragma unroll
    for (int mt = 0; mt < 4; ++mt) {
        int tok = mt * 16 + l15; if (tok > 48) tok = 48;
        const unsigned short* qp = &qkvb[(size_t)(g0 + tok) * 288 + h * HDM + g4 * 8];
        aq[mt] = *reinterpret_cast<const s8v*>(qp);        // Q (pre-scaled)
        bk[mt] = *reinterpret_cast<const s8v*>(qp + 96);   // K
    }

    fx4 sc[4][4];
    #pragma unroll
    for (int mt = 0; mt < 4; ++mt)
        #pragma unroll
        for (int nt = 0; nt < 4; ++nt)
            sc[mt][nt] = MFMA16(aq[mt], bk[nt], ((fx4){0.f,0.f,0.f,0.f}));

    #pragma unroll
    for (int mt = 0; mt < 4; ++mt) {
        fx4 bmv[4];
        #pragma unroll
        for (int nt = 0; nt < 4; ++nt)
            bmv[nt] = *reinterpret_cast<const fx4*>(&BMF[((mt * 4 + nt) << 8) + lane * 4]);
        #pragma unroll
        for (int r = 0; r < 4; ++r) {
            float rs1 = 0.f;
            #pragma unroll
            for (int nt = 0; nt < 4; ++nt) {
                const int n = nt * 16 + l15;
                float s = sc[mt][nt][r] + bmv[nt][r];
                float e = (n < NTK) ? __expf(s) : 0.f;
                sc[mt][nt][r] = e;
                rs1 += e;
            }
            rs1 += __shfl_xor(rs1, 1); rs1 += __shfl_xor(rs1, 2);
            rs1 += __shfl_xor(rs1, 4); rs1 += __shfl_xor(rs1, 8);
            const float iv1 = 1.f / rs1;
            float rs2 = 0.f;
            #pragma unroll
            for (int nt = 0; nt < 4; ++nt) {
                const int n = nt * 16 + l15;
                float e2 = (n < NTK) ? __expf(sc[mt][nt][r] * iv1) : 0.f;
                sc[mt][nt][r] = e2;
                rs2 += e2;
            }
            rs2 += __shfl_xor(rs2, 1); rs2 += __shfl_xor(rs2, 2);
            rs2 += __shfl_xor(rs2, 4); rs2 += __shfl_xor(rs2, 8);
            const float iv2 = 1.f / rs2;
            const int m = mt * 16 + g4 * 4 + r;
            #pragma unroll
            for (int nt = 0; nt < 4; ++nt)
                P[m][nt * 16 + l15] = f2bf(sc[mt][nt][r] * iv2);
        }
    }
    __syncthreads();

    fx4 oc[4][2];
    #pragma unroll
    for (int mt = 0; mt < 4; ++mt) { oc[mt][0] = (fx4){0.f,0.f,0.f,0.f}; oc[mt][1] = (fx4){0.f,0.f,0.f,0.f}; }
    #pragma unroll
    for (int ks = 0; ks < 2; ++ks) {
        s8v vb[2];
        #pragma unroll
        for (int nt = 0; nt < 2; ++nt) {
            union { s8v v; unsigned short u[8]; } pv;
            #pragma unroll
            for (int j = 0; j < 8; ++j) {
                int tok = ks * 32 + g4 * 8 + j; if (tok > 48) tok = 48;
                pv.u[j] = qkvb[(size_t)(g0 + tok) * 288 + 192 + h * HDM + nt * 16 + l15];
            }
            vb[nt] = pv.v;
        }
        #pragma unroll
        for (int mt = 0; mt < 4; ++mt) {
            s8v pa = *reinterpret_cast<const s8v*>(&P[mt * 16 + l15][ks * 32 + g4 * 8]);
            oc[mt][0] = MFMA16(pa, vb[0], oc[mt][0]);
            oc[mt][1] = MFMA16(pa, vb[1], oc[mt][1]);
        }
    }
    #pragma unroll
    for (int mt = 0; mt < 4; ++mt) {
        #pragma unroll
        for (int r = 0; r < 4; ++r) {
            const int m = mt * 16 + g4 * 4 + r;
            if (m < NTK) {
                qkvb[(size_t)(g0 + m) * 288 + h * HDM + l15]      = f2bf(oc[mt][0][r]);
                qkvb[(size_t)(g0 + m) * 288 + h * HDM + 16 + l15] = f2bf(oc[mt][1][r]);
            }
        }
    }
}

// ---------- K2b: barrier-free proj GEMM + residual + un-shift scatter ----------
extern "C" __global__ void __launch_bounds__(256, 3) k2b_proj(
    const unsigned short* __restrict__ qkvb, const unsigned short* __restrict__ pwtf,
    const float* __restrict__ pb, const float* __restrict__ x, float* __restrict__ out)
{
    const int tid = threadIdx.x, wave = tid >> 6, lane = tid & 63;
    const int l15 = lane & 15, g4 = lane >> 4;
    const int row0 = blockIdx.x * 64 + wave * 16;

    const unsigned short* arow = qkvb + (size_t)(row0 + l15) * 288 + g4 * 8;
    s8v a[3];
    a[0] = *reinterpret_cast<const s8v*>(arow);
    a[1] = *reinterpret_cast<const s8v*>(arow + 32);
    a[2] = *reinterpret_cast<const s8v*>(arow + 64);

    fx4 acc[6];
    #pragma unroll
    for (int nt = 0; nt < 6; ++nt) acc[nt] = (fx4){0.f,0.f,0.f,0.f};
    #pragma unroll
    for (int ks = 0; ks < 3; ++ks) {
        #pragma unroll
        for (int nt = 0; nt < 6; ++nt) {
            s8v b = *reinterpret_cast<const s8v*>(&pwtf[((nt * 3 + ks) * 64 + lane) * 8]);
            acc[nt] = MFMA16(a[ks], b, acc[nt]);
        }
    }
    int orig[4];
    #pragma unroll
    for (int r = 0; r < 4; ++r)
        orig[r] = wtok_to_orig(row0 + g4 * 4 + r);
    #pragma unroll
    for (int nt = 0; nt < 6; ++nt) {
        const int col = nt * 16 + l15;
        const float pbc = pb[col];
        #pragma unroll
        for (int r = 0; r < 4; ++r) {
            const size_t idx = (size_t)orig[r] * CC + col;
            out[idx] = acc[nt][r] + pbc + x[idx];
        }
    }
}

// ---------- K3: barrier-free MLP (R15 form, unroll 1) + op-minimized gelu ----------
#define LDA 72
extern "C" __global__ void __launch_bounds__(256, 3) k3_mlp(
    float* __restrict__ xio, const float* __restrict__ g2, const float* __restrict__ b2,
    const unsigned short* __restrict__ w1f, const float* __restrict__ bf1,
    const unsigned short* __restrict__ w2f, const float* __restrict__ bf2)
{
    __shared__ unsigned short Ac[64 * LDA];    // 9216 B, wave-private rows
    const int tid = threadIdx.x, wave = tid >> 6, lane = tid & 63;
    const int l15 = lane & 15, g4 = lane >> 4;
    const int row0 = blockIdx.x * 64 + wave * 16;

    s8v ha[3];
    ln_frag(xio + (size_t)(row0 + l15) * CC, g2, b2, g4, ha);

    fx4 oacc[6];
    #pragma unroll
    for (int nt = 0; nt < 6; ++nt) oacc[nt] = (fx4){0.f,0.f,0.f,0.f};

    #pragma unroll 1
    for (int ck = 0; ck < 6; ++ck) {
        fx4 a1[4];
        #pragma unroll
        for (int nt = 0; nt < 4; ++nt) a1[nt] = (fx4){0.f,0.f,0.f,0.f};
        #pragma unroll
        for (int ks = 0; ks < 3; ++ks) {
            #pragma unroll
            for (int nt = 0; nt < 4; ++nt) {
                s8v b = *reinterpret_cast<const s8v*>(
                    &w1f[(((ck * 4 + nt) * 3 + ks) * 64 + lane) * 8]);
                a1[nt] = MFMA16(ha[ks], b, a1[nt]);
            }
        }
        #pragma unroll
        for (int nt = 0; nt < 4; ++nt) {
            const float bb = bf1[ck * 64 + nt * 16 + l15];
            #pragma unroll
            for (int r = 0; r < 4; ++r) {
                float v0 = a1[nt][r] + bb;
                Ac[(wave*16 + g4*4 + r) * LDA + nt*16 + l15] = f2bf(gelu_t(gelu_t(v0)));
            }
        }
        #pragma unroll
        for (int ks = 0; ks < 2; ++ks) {
            s8v a = *reinterpret_cast<const s8v*>(&Ac[(wave*16 + l15)*LDA + ks*32 + g4*8]);
            #pragma unroll
            for (int nt = 0; nt < 6; ++nt) {
                s8v b = *reinterpret_cast<const s8v*>(
                    &w2f[(((ck * 6 + nt) * 2 + ks) * 64 + lane) * 8]);
                oacc[nt] = MFMA16(a, b, oacc[nt]);
            }
        }
    }

    const int rowb = row0 + g4 * 4;
    #pragma unroll
    for (int nt = 0; nt < 6; ++nt) {
        const int col = nt * 16 + l15;
        const float bb = bf2[col];
        #pragma unroll
        for (int r = 0; r < 4; ++r) {
            const size_t idx = (size_t)(rowb + r) * CC + col;
            xio[idx] = xio[idx] + oacc[nt][r] + bb;
        }
    }
}

extern "C" void kernel_launch(void* const* d_in, const int* in_sizes, int n_in,
                              void* d_out, int out_size, void* d_ws, size_t ws_size,
                              hipStream_t stream)
{
    const float* x    = (const float*)d_in[0];
    const float* n1g  = (const float*)d_in[1];
    const float* n1b  = (const float*)d_in[2];
    const float* qw   = (const float*)d_in[3];
    const float* qb   = (const float*)d_in[4];
    const float* btab = (const float*)d_in[5];
    const float* pw   = (const float*)d_in[6];
    const float* pb   = (const float*)d_in[7];
    const float* n2g  = (const float*)d_in[8];
    const float* n2b  = (const float*)d_in[9];
    const float* w1   = (const float*)d_in[10];
    const float* bf1  = (const float*)d_in[11];
    const float* w2   = (const float*)d_in[12];
    const float* bf2  = (const float*)d_in[13];
    float* out = (float*)d_out;

    unsigned short* qkvb = (unsigned short*)d_ws;                 // TOT*288 bf16 = 57.8 MB
    unsigned short* wbf  = qkvb + (size_t)TOT * 288;
    unsigned short* qwtf = wbf;                                   // 27648 frag-linear
    unsigned short* pwtf = qwtf + 27648;                          // 9216 frag-linear
    unsigned short* w1f  = pwtf + 9216;                           // 36864 frag-linear
    unsigned short* w2f  = w1f + 36864;                           // 36864 frag-linear
    float* bmf = (float*)(wbf + 110592);                          // 49152 fp32 (D-frag)

    p0_prep <<<624, 256, 0, stream>>>(qw, pw, w1, w2, btab, wbf);
    k1_qkv  <<<TOT/64, 256, 0, stream>>>(x, n1g, n1b, qwtf, qb, qkvb);
    k2_attn <<<BB*NWIN*NHD, 64, 0, stream>>>(qkvb, bmf);
    k2b_proj<<<TOT/64, 256, 0, stream>>>(qkvb, pwtf, pb, x, out);
    k3_mlp  <<<TOT/64, 256, 0, stream>>>(out, n2g, n2b, w1f, bf1, w2f, bf2);
}

// Round 22
// 126.723 us; speedup vs baseline: 1.3698x; 1.1256x over previous
//
#include <hip/hip_runtime.h>
#include <math.h>

#define BB   32
#define HH   56
#define WWI  56
#define CC   96
#define NHD  3
#define WSZ  7
#define SHF  3
#define NTK  49
#define NWIN 64
#define HDM  32
#define TOT  (BB*HH*WWI)               // 100352
#define QKSCALE 0.17677669529663687f
#define LEPS 1e-3f

typedef __attribute__((ext_vector_type(8))) short s8v;   // 8 bf16 (4 VGPRs)
typedef __attribute__((ext_vector_type(4))) float fx4;   // 4 fp32
typedef unsigned long long ull_t;

#define MFMA16(a,b,c) __builtin_amdgcn_mfma_f32_16x16x32_bf16((a),(b),(c),0,0,0)

__device__ __forceinline__ unsigned short f2bf(float f) {
    union { float f; unsigned u; } v; v.f = f;
    unsigned r = v.u + 0x7FFFu + ((v.u >> 16) & 1u);
    return (unsigned short)(r >> 16);
}

// sigmoid-form gelu, op-minimized (R21: k3 65->62us)
__device__ __forceinline__ float gelu_t(float x) {
    float x2 = x * x;
#if __has_builtin(__builtin_amdgcn_exp2f)
    float z = x * fmaf(-0.10294326f, x2, -2.3022082f);   // -log2(e)*1.59577*(1, .044715)
    float e = __builtin_amdgcn_exp2f(z);
#else
    float z = x * fmaf(-0.07135529f, x2, -1.5957691f);
    float e = __expf(z);
#endif
    return x * __builtin_amdgcn_rcpf(1.f + e);
}

// windowed token id -> original flat token id (roll(-3,-3) + window partition)
__device__ __forceinline__ int wtok_to_orig(int wt) {
    int win = wt / NTK;
    int p   = wt - win * NTK;
    int b   = win >> 6;
    int w   = win & 63;
    int wi = w >> 3, wj = w & 7;
    int pi = p / WSZ, pj = p - pi * WSZ;
    int r = wi * WSZ + pi + SHF; if (r >= HH) r -= HH;
    int c = wj * WSZ + pj + SHF; if (c >= WWI) c -= WWI;
    return b * (HH * WWI) + r * WWI + c;
}

// LayerNorm in MFMA-A-fragment layout (reduction via shfl_xor 16/32)
__device__ __forceinline__ void ln_frag(const float* __restrict__ row,
                                        const float* __restrict__ gg,
                                        const float* __restrict__ bb,
                                        int g4, s8v ha[3])
{
    float h[24];
    #pragma unroll
    for (int ks = 0; ks < 3; ++ks) {
        fx4 v0 = *reinterpret_cast<const fx4*>(row + ks * 32 + g4 * 8);
        fx4 v1 = *reinterpret_cast<const fx4*>(row + ks * 32 + g4 * 8 + 4);
        h[ks*8+0]=v0.x; h[ks*8+1]=v0.y; h[ks*8+2]=v0.z; h[ks*8+3]=v0.w;
        h[ks*8+4]=v1.x; h[ks*8+5]=v1.y; h[ks*8+6]=v1.z; h[ks*8+7]=v1.w;
    }
    float s = 0.f, s2 = 0.f;
    #pragma unroll
    for (int j = 0; j < 24; ++j) { s += h[j]; s2 = fmaf(h[j], h[j], s2); }
    s  += __shfl_xor(s, 16);  s  += __shfl_xor(s, 32);
    s2 += __shfl_xor(s2, 16); s2 += __shfl_xor(s2, 32);
    const float mu = s * (1.f/CC);
    const float rs = rsqrtf(s2 * (1.f/CC) - mu * mu + LEPS);
    #pragma unroll
    for (int ks = 0; ks < 3; ++ks) {
        union { s8v v; unsigned short u[8]; } p;
        #pragma unroll
        for (int j = 0; j < 8; ++j) {
            int c = ks * 32 + g4 * 8 + j;
            p.u[j] = f2bf((h[ks*8+j] - mu) * rs * gg[c] + bb[c]);
        }
        ha[ks] = p.v;
    }
}

// ---------- P0: weights frag-linearized + BM in D-fragment layout ----------
extern "C" __global__ void p0_prep(const float* __restrict__ qw, const float* __restrict__ pw,
                                   const float* __restrict__ w1, const float* __restrict__ w2,
                                   const float* __restrict__ btab,
                                   unsigned short* __restrict__ wsw)
{
    int i = blockIdx.x * 256 + threadIdx.x;
    if (i < 27648) {                       // qwtf frag-linear
        int e = i & 7, f = i >> 3;
        int lane = f & 63, fid = f >> 6;   // fid 0..53
        int ks = fid % 3, t = fid / 3;
        int nt = t % 6, ck = t / 6;
        int n = ck * 96 + nt * 16 + (lane & 15);
        int k = ks * 32 + (lane >> 4) * 8 + e;
        float v = qw[k * 288 + n];
        if (n < 96) v *= QKSCALE;
        wsw[i] = f2bf(v);
    } else if (i < 36864) {                // pwtf frag-linear
        int j = i - 27648;
        int e = j & 7, f = j >> 3;
        int lane = f & 63, fid = f >> 6;   // fid 0..17
        int ks = fid % 3, nt = fid / 3;
        int n = nt * 16 + (lane & 15);
        int k = ks * 32 + (lane >> 4) * 8 + e;
        wsw[i] = f2bf(pw[k * 96 + n]);
    } else if (i < 73728) {                // w1f frag-linear
        int j = i - 36864;
        int e = j & 7, f = j >> 3;
        int lane = f & 63, fid = f >> 6;
        int ks = fid % 3, t = fid / 3;
        int nt = t & 3, ck = t >> 2;
        int n = ck * 64 + nt * 16 + (lane & 15);
        int k = ks * 32 + (lane >> 4) * 8 + e;
        wsw[i] = f2bf(w1[k * 384 + n]);
    } else if (i < 110592) {               // w2f frag-linear
        int j = i - 73728;
        int e = j & 7, f = j >> 3;
        int lane = f & 63, fid = f >> 6;
        int ks = fid & 1, t = fid >> 1;
        int nt = t % 6, ck = t / 6;
        int n = nt * 16 + (lane & 15);
        int k = ck * 64 + ks * 32 + (lane >> 4) * 8 + e;
        wsw[i] = f2bf(w2[k * 96 + n]);
    } else if (i < 159744) {               // bmf: BM in D-frag layout (fp32)
        float* bmf = (float*)(wsw + 110592);
        int j = i - 110592;                // 0..49151
        int r = j & 3, lane = (j >> 2) & 63;
        int fid = j >> 8;                  // 0..191
        int mtnt = fid & 15, t = fid >> 4; // t 0..11
        int mt = mtnt >> 2, nt = mtnt & 3;
        int hd = t % 3, cls = t / 3;
        int m = mt * 16 + (lane >> 4) * 4 + r; if (m > 48) m = 48;
        int n = nt * 16 + (lane & 15);
        float val = 0.f;
        if (n < 49) {
            int it = m / 7, jt = m - it * 7;
            int iu = n / 7, ju = n - iu * 7;
            int li  = (cls & 2) ? (it < 4 ? 1 : 2) : 0;
            int lj  = (cls & 1) ? (jt < 4 ? 1 : 2) : 0;
            int lui = (cls & 2) ? (iu < 4 ? 1 : 2) : 0;
            int luj = (cls & 1) ? (ju < 4 ? 1 : 2) : 0;
            int bidx = (jt - ju + 6) * 13 + (it - iu + 6);
            val = btab[bidx * 3 + hd] + ((li*3+lj) == (lui*3+luj) ? 0.f : -100.f);
        }
        bmf[j] = val;
    }
}

// ---------- K1: barrier-free gather + LN1(frag) + QKV MFMA -> qkvb bf16 ----------
extern "C" __global__ void __launch_bounds__(256, 3) k1_qkv(
    const float* __restrict__ x, const float* __restrict__ g1, const float* __restrict__ b1,
    const unsigned short* __restrict__ qwtf, const float* __restrict__ qb,
    unsigned short* __restrict__ qkvb)
{
    const int tid = threadIdx.x, wave = tid >> 6, lane = tid & 63;
    const int l15 = lane & 15, g4 = lane >> 4;
    const int row0 = blockIdx.x * 64 + wave * 16;

    s8v ha[3];
    {
        const int orig = wtok_to_orig(row0 + l15);
        ln_frag(x + (size_t)orig * CC, g1, b1, g4, ha);
    }

    #pragma unroll
    for (int ck = 0; ck < 3; ++ck) {
        fx4 acc[6];
        #pragma unroll
        for (int nt = 0; nt < 6; ++nt) acc[nt] = (fx4){0.f,0.f,0.f,0.f};
        #pragma unroll
        for (int ks = 0; ks < 3; ++ks) {
            #pragma unroll
            for (int nt = 0; nt < 6; ++nt) {
                s8v b = *reinterpret_cast<const s8v*>(
                    &qwtf[(((ck * 6 + nt) * 3 + ks) * 64 + lane) * 8]);
                acc[nt] = MFMA16(ha[ks], b, acc[nt]);
            }
        }
        const int rowb = row0 + g4 * 4;
        const float qmul = (ck == 0) ? QKSCALE : 1.f;   // qb scale matches scaled qwtf
        #pragma unroll
        for (int nt = 0; nt < 6; ++nt) {
            const int col = ck * 96 + nt * 16 + l15;
            const float qbc = qb[col] * qmul;
            #pragma unroll
            for (int r = 0; r < 4; ++r)
                qkvb[(size_t)(rowb + r) * 288 + col] = f2bf(acc[nt][r] + qbc);
        }
    }
}

// ---------- K2: MFMA attention; V scalar-gather, bias+mask via bmf; (64,3) ----------
extern "C" __global__ void __launch_bounds__(64, 3) k2_attn(
    unsigned short* __restrict__ qkvb, const float* __restrict__ bmf)
{
    __shared__ unsigned short P[64][72];   // 9216 B
    const int lane = threadIdx.x;
    const int l15 = lane & 15, g4 = lane >> 4;
    const int task = blockIdx.x;
    const int win = task / 3, h = task - win * 3;
    const int g0  = win * NTK;
    const int w   = win & 63;
    const int cls = (((w >> 3) == 7) ? 2 : 0) + (((w & 7) == 7) ? 1 : 0);
    const float* BMF = bmf + (size_t)(cls * 3 + h) * 4096;

    s8v aq[4], bk[4];
    #pragma unroll
    for (int mt = 0; mt < 4; ++mt) {
        int tok = mt * 16 + l15; if (tok > 48) tok = 48;
        const unsigned short* qp = &qkvb[(size_t)(g0 + tok) * 288 + h * HDM + g4 * 8];
        aq[mt] = *reinterpret_cast<const s8v*>(qp);        // Q (pre-scaled)
        bk[mt] = *reinterpret_cast<const s8v*>(qp + 96);   // K
    }

    fx4 sc[4][4];
    #pragma unroll
    for (int mt = 0; mt < 4; ++mt)
        #pragma unroll
        for (int nt = 0; nt < 4; ++nt)
            sc[mt][nt] = MFMA16(aq[mt], bk[nt], ((fx4){0.f,0.f,0.f,0.f}));

    #pragma unroll
    for (int mt = 0; mt < 4; ++mt) {
        fx4 bmv[4];
        #pragma unroll
        for (int nt = 0; nt < 4; ++nt)
            bmv[nt] = *reinterpret_cast<const fx4*>(&BMF[((mt * 4 + nt) << 8) + lane * 4]);
        #pragma unroll
        for (int r = 0; r < 4; ++r) {
            float rs1 = 0.f;
            #pragma unroll
            for (int nt = 0; nt < 4; ++nt) {
                const int n = nt * 16 + l15;
                float s = sc[mt][nt][r] + bmv[nt][r];
                float e = (n < NTK) ? __expf(s) : 0.f;
                sc[mt][nt][r] = e;
                rs1 += e;
            }
            rs1 += __shfl_xor(rs1, 1); rs1 += __shfl_xor(rs1, 2);
            rs1 += __shfl_xor(rs1, 4); rs1 += __shfl_xor(rs1, 8);
            const float iv1 = 1.f / rs1;
            float rs2 = 0.f;
            #pragma unroll
            for (int nt = 0; nt < 4; ++nt) {
                const int n = nt * 16 + l15;
                float e2 = (n < NTK) ? __expf(sc[mt][nt][r] * iv1) : 0.f;
                sc[mt][nt][r] = e2;
                rs2 += e2;
            }
            rs2 += __shfl_xor(rs2, 1); rs2 += __shfl_xor(rs2, 2);
            rs2 += __shfl_xor(rs2, 4); rs2 += __shfl_xor(rs2, 8);
            const float iv2 = 1.f / rs2;
            const int m = mt * 16 + g4 * 4 + r;
            #pragma unroll
            for (int nt = 0; nt < 4; ++nt)
                P[m][nt * 16 + l15] = f2bf(sc[mt][nt][r] * iv2);
        }
    }
    __syncthreads();

    fx4 oc[4][2];
    #pragma unroll
    for (int mt = 0; mt < 4; ++mt) { oc[mt][0] = (fx4){0.f,0.f,0.f,0.f}; oc[mt][1] = (fx4){0.f,0.f,0.f,0.f}; }
    #pragma unroll
    for (int ks = 0; ks < 2; ++ks) {
        s8v vb[2];
        #pragma unroll
        for (int nt = 0; nt < 2; ++nt) {
            union { s8v v; unsigned short u[8]; } pv;
            #pragma unroll
            for (int j = 0; j < 8; ++j) {
                int tok = ks * 32 + g4 * 8 + j; if (tok > 48) tok = 48;
                pv.u[j] = qkvb[(size_t)(g0 + tok) * 288 + 192 + h * HDM + nt * 16 + l15];
            }
            vb[nt] = pv.v;
        }
        #pragma unroll
        for (int mt = 0; mt < 4; ++mt) {
            s8v pa = *reinterpret_cast<const s8v*>(&P[mt * 16 + l15][ks * 32 + g4 * 8]);
            oc[mt][0] = MFMA16(pa, vb[0], oc[mt][0]);
            oc[mt][1] = MFMA16(pa, vb[1], oc[mt][1]);
        }
    }
    #pragma unroll
    for (int mt = 0; mt < 4; ++mt) {
        #pragma unroll
        for (int r = 0; r < 4; ++r) {
            const int m = mt * 16 + g4 * 4 + r;
            if (m < NTK) {
                qkvb[(size_t)(g0 + m) * 288 + h * HDM + l15]      = f2bf(oc[mt][0][r]);
                qkvb[(size_t)(g0 + m) * 288 + h * HDM + 16 + l15] = f2bf(oc[mt][1][r]);
            }
        }
    }
}

// ---------- K23: fused proj + residual + LN2 + MLP + residual ----------
// Works in orig-token order; o-rows gathered via inverse shift map. x2 = proj+x
// stays on-chip in wave-private LDS (fp32) -> saves the 38MB out-write and
// 38MB re-read of the split k2b/k3 pair, plus one kernel ramp.
#define LDA 72
#define LDX2 100   // pad: row stride 400B -> 2-way-free banks on b128 reads
extern "C" __global__ void __launch_bounds__(256, 3) k23_fused(
    const unsigned short* __restrict__ qkvb, const unsigned short* __restrict__ pwtf,
    const float* __restrict__ pb, const float* __restrict__ x,
    const float* __restrict__ g2, const float* __restrict__ b2,
    const unsigned short* __restrict__ w1f, const float* __restrict__ bf1,
    const unsigned short* __restrict__ w2f, const float* __restrict__ bf2,
    float* __restrict__ out)
{
    __shared__ float X2[64][LDX2];             // 25600 B, wave-private rows
    __shared__ unsigned short Ac[64 * LDA];    // 9216 B  (total 34816)
    const int tid = threadIdx.x, wave = tid >> 6, lane = tid & 63;
    const int l15 = lane & 15, g4 = lane >> 4;
    const int row0 = blockIdx.x * 64 + wave * 16;   // orig-token rows

    // ---- proj: A-frags from qkvb row of the mapped windowed token ----
    s8v a[3];
    {
        const int t = row0 + l15;
        const int b = t / (HH * WWI), rc = t - b * (HH * WWI);
        const int orr = rc / WWI, occ = rc - orr * WWI;
        int wr = orr + (HH - SHF); if (wr >= HH) wr -= HH;
        int wc = occ + (WWI - SHF); if (wc >= WWI) wc -= WWI;
        const int wtok = (b * 64 + (wr / WSZ) * 8 + (wc / WSZ)) * NTK
                         + (wr % WSZ) * WSZ + (wc % WSZ);
        const unsigned short* arow = qkvb + (size_t)wtok * 288 + g4 * 8;
        a[0] = *reinterpret_cast<const s8v*>(arow);
        a[1] = *reinterpret_cast<const s8v*>(arow + 32);
        a[2] = *reinterpret_cast<const s8v*>(arow + 64);
    }
    {
        fx4 acc[6];
        #pragma unroll
        for (int nt = 0; nt < 6; ++nt) acc[nt] = (fx4){0.f,0.f,0.f,0.f};
        #pragma unroll
        for (int ks = 0; ks < 3; ++ks) {
            #pragma unroll
            for (int nt = 0; nt < 6; ++nt) {
                s8v b = *reinterpret_cast<const s8v*>(&pwtf[((nt * 3 + ks) * 64 + lane) * 8]);
                acc[nt] = MFMA16(a[ks], b, acc[nt]);
            }
        }
        // x2 = proj + pb + x -> LDS (D-frag indexing; x read is LINEAR in orig order)
        #pragma unroll
        for (int nt = 0; nt < 6; ++nt) {
            const int col = nt * 16 + l15;
            const float pbc = pb[col];
            #pragma unroll
            for (int r = 0; r < 4; ++r) {
                const int tr = row0 + g4 * 4 + r;
                X2[wave * 16 + g4 * 4 + r][col] = acc[nt][r] + pbc + x[(size_t)tr * CC + col];
            }
        }
    }

    // ---- LN2 from LDS (wave-private: in-wave lgkmcnt ordering suffices) ----
    s8v ha[3];
    ln_frag(&X2[wave * 16 + l15][0], g2, b2, g4, ha);

    fx4 oacc[6];
    #pragma unroll
    for (int nt = 0; nt < 6; ++nt) oacc[nt] = (fx4){0.f,0.f,0.f,0.f};

    #pragma unroll 1
    for (int ck = 0; ck < 6; ++ck) {
        fx4 a1[4];
        #pragma unroll
        for (int nt = 0; nt < 4; ++nt) a1[nt] = (fx4){0.f,0.f,0.f,0.f};
        #pragma unroll
        for (int ks = 0; ks < 3; ++ks) {
            #pragma unroll
            for (int nt = 0; nt < 4; ++nt) {
                s8v b = *reinterpret_cast<const s8v*>(
                    &w1f[(((ck * 4 + nt) * 3 + ks) * 64 + lane) * 8]);
                a1[nt] = MFMA16(ha[ks], b, a1[nt]);
            }
        }
        #pragma unroll
        for (int nt = 0; nt < 4; ++nt) {
            const float bb = bf1[ck * 64 + nt * 16 + l15];
            #pragma unroll
            for (int r = 0; r < 4; ++r) {
                float v0 = a1[nt][r] + bb;
                Ac[(wave*16 + g4*4 + r) * LDA + nt*16 + l15] = f2bf(gelu_t(gelu_t(v0)));
            }
        }
        #pragma unroll
        for (int ks = 0; ks < 2; ++ks) {
            s8v aa = *reinterpret_cast<const s8v*>(&Ac[(wave*16 + l15)*LDA + ks*32 + g4*8]);
            #pragma unroll
            for (int nt = 0; nt < 6; ++nt) {
                s8v b = *reinterpret_cast<const s8v*>(
                    &w2f[(((ck * 6 + nt) * 2 + ks) * 64 + lane) * 8]);
                oacc[nt] = MFMA16(aa, b, oacc[nt]);
            }
        }
    }

    // ---- final: out = x2 + mlp + bf2 (X2 read back at the written indices) ----
    const int rowb = row0 + g4 * 4;
    #pragma unroll
    for (int nt = 0; nt < 6; ++nt) {
        const int col = nt * 16 + l15;
        const float bb = bf2[col];
        #pragma unroll
        for (int r = 0; r < 4; ++r) {
            out[(size_t)(rowb + r) * CC + col] =
                X2[wave * 16 + g4 * 4 + r][col] + oacc[nt][r] + bb;
        }
    }
}

extern "C" void kernel_launch(void* const* d_in, const int* in_sizes, int n_in,
                              void* d_out, int out_size, void* d_ws, size_t ws_size,
                              hipStream_t stream)
{
    const float* x    = (const float*)d_in[0];
    const float* n1g  = (const float*)d_in[1];
    const float* n1b  = (const float*)d_in[2];
    const float* qw   = (const float*)d_in[3];
    const float* qb   = (const float*)d_in[4];
    const float* btab = (const float*)d_in[5];
    const float* pw   = (const float*)d_in[6];
    const float* pb   = (const float*)d_in[7];
    const float* n2g  = (const float*)d_in[8];
    const float* n2b  = (const float*)d_in[9];
    const float* w1   = (const float*)d_in[10];
    const float* bf1  = (const float*)d_in[11];
    const float* w2   = (const float*)d_in[12];
    const float* bf2  = (const float*)d_in[13];
    float* out = (float*)d_out;

    unsigned short* qkvb = (unsigned short*)d_ws;                 // TOT*288 bf16 = 57.8 MB
    unsigned short* wbf  = qkvb + (size_t)TOT * 288;
    unsigned short* qwtf = wbf;                                   // 27648 frag-linear
    unsigned short* pwtf = qwtf + 27648;                          // 9216 frag-linear
    unsigned short* w1f  = pwtf + 9216;                           // 36864 frag-linear
    unsigned short* w2f  = w1f + 36864;                           // 36864 frag-linear
    float* bmf = (float*)(wbf + 110592);                          // 49152 fp32 (D-frag)

    p0_prep  <<<624, 256, 0, stream>>>(qw, pw, w1, w2, btab, wbf);
    k1_qkv   <<<TOT/64, 256, 0, stream>>>(x, n1g, n1b, qwtf, qb, qkvb);
    k2_attn  <<<BB*NWIN*NHD, 64, 0, stream>>>(qkvb, bmf);
    k23_fused<<<TOT/64, 256, 0, stream>>>(qkvb, pwtf, pb, x, n2g, n2b,
                                          w1f, bf1, w2f, bf2, out);
}

// Round 23
// 121.188 us; speedup vs baseline: 1.4323x; 1.0457x over previous
//
#include <hip/hip_runtime.h>
#include <math.h>

#define BB   32
#define HH   56
#define WWI  56
#define CC   96
#define NHD  3
#define WSZ  7
#define SHF  3
#define NTK  49
#define NWIN 64
#define HDM  32
#define TOT  (BB*HH*WWI)               // 100352
#define QKSCALE 0.17677669529663687f
#define LEPS 1e-3f

typedef __attribute__((ext_vector_type(8))) short s8v;   // 8 bf16 (4 VGPRs)
typedef __attribute__((ext_vector_type(4))) float fx4;   // 4 fp32
typedef unsigned long long ull_t;

#define MFMA16(a,b,c) __builtin_amdgcn_mfma_f32_16x16x32_bf16((a),(b),(c),0,0,0)

__device__ __forceinline__ unsigned short f2bf(float f) {
    union { float f; unsigned u; } v; v.f = f;
    unsigned r = v.u + 0x7FFFu + ((v.u >> 16) & 1u);
    return (unsigned short)(r >> 16);
}

// sigmoid-form gelu, op-minimized (R21)
__device__ __forceinline__ float gelu_t(float x) {
    float x2 = x * x;
#if __has_builtin(__builtin_amdgcn_exp2f)
    float z = x * fmaf(-0.10294326f, x2, -2.3022082f);   // -log2(e)*1.59577*(1, .044715)
    float e = __builtin_amdgcn_exp2f(z);
#else
    float z = x * fmaf(-0.07135529f, x2, -1.5957691f);
    float e = __expf(z);
#endif
    return x * __builtin_amdgcn_rcpf(1.f + e);
}

// windowed token id -> original flat token id (roll(-3,-3) + window partition)
__device__ __forceinline__ int wtok_to_orig(int wt) {
    int win = wt / NTK;
    int p   = wt - win * NTK;
    int b   = win >> 6;
    int w   = win & 63;
    int wi = w >> 3, wj = w & 7;
    int pi = p / WSZ, pj = p - pi * WSZ;
    int r = wi * WSZ + pi + SHF; if (r >= HH) r -= HH;
    int c = wj * WSZ + pj + SHF; if (c >= WWI) c -= WWI;
    return b * (HH * WWI) + r * WWI + c;
}

// LayerNorm in MFMA-A-fragment layout (reduction via shfl_xor 16/32)
__device__ __forceinline__ void ln_frag(const float* __restrict__ row,
                                        const float* __restrict__ gg,
                                        const float* __restrict__ bb,
                                        int g4, s8v ha[3])
{
    float h[24];
    #pragma unroll
    for (int ks = 0; ks < 3; ++ks) {
        fx4 v0 = *reinterpret_cast<const fx4*>(row + ks * 32 + g4 * 8);
        fx4 v1 = *reinterpret_cast<const fx4*>(row + ks * 32 + g4 * 8 + 4);
        h[ks*8+0]=v0.x; h[ks*8+1]=v0.y; h[ks*8+2]=v0.z; h[ks*8+3]=v0.w;
        h[ks*8+4]=v1.x; h[ks*8+5]=v1.y; h[ks*8+6]=v1.z; h[ks*8+7]=v1.w;
    }
    float s = 0.f, s2 = 0.f;
    #pragma unroll
    for (int j = 0; j < 24; ++j) { s += h[j]; s2 = fmaf(h[j], h[j], s2); }
    s  += __shfl_xor(s, 16);  s  += __shfl_xor(s, 32);
    s2 += __shfl_xor(s2, 16); s2 += __shfl_xor(s2, 32);
    const float mu = s * (1.f/CC);
    const float rs = rsqrtf(s2 * (1.f/CC) - mu * mu + LEPS);
    #pragma unroll
    for (int ks = 0; ks < 3; ++ks) {
        union { s8v v; unsigned short u[8]; } p;
        #pragma unroll
        for (int j = 0; j < 8; ++j) {
            int c = ks * 32 + g4 * 8 + j;
            p.u[j] = f2bf((h[ks*8+j] - mu) * rs * gg[c] + bb[c]);
        }
        ha[ks] = p.v;
    }
}

// ---------- P0: weights frag-linearized + BM in D-fragment layout ----------
extern "C" __global__ void p0_prep(const float* __restrict__ qw, const float* __restrict__ pw,
                                   const float* __restrict__ w1, const float* __restrict__ w2,
                                   const float* __restrict__ btab,
                                   unsigned short* __restrict__ wsw)
{
    int i = blockIdx.x * 256 + threadIdx.x;
    if (i < 27648) {                       // qwtf frag-linear
        int e = i & 7, f = i >> 3;
        int lane = f & 63, fid = f >> 6;   // fid 0..53
        int ks = fid % 3, t = fid / 3;
        int nt = t % 6, ck = t / 6;
        int n = ck * 96 + nt * 16 + (lane & 15);
        int k = ks * 32 + (lane >> 4) * 8 + e;
        float v = qw[k * 288 + n];
        if (n < 96) v *= QKSCALE;
        wsw[i] = f2bf(v);
    } else if (i < 36864) {                // pwtf frag-linear
        int j = i - 27648;
        int e = j & 7, f = j >> 3;
        int lane = f & 63, fid = f >> 6;   // fid 0..17
        int ks = fid % 3, nt = fid / 3;
        int n = nt * 16 + (lane & 15);
        int k = ks * 32 + (lane >> 4) * 8 + e;
        wsw[i] = f2bf(pw[k * 96 + n]);
    } else if (i < 73728) {                // w1f frag-linear
        int j = i - 36864;
        int e = j & 7, f = j >> 3;
        int lane = f & 63, fid = f >> 6;
        int ks = fid % 3, t = fid / 3;
        int nt = t & 3, ck = t >> 2;
        int n = ck * 64 + nt * 16 + (lane & 15);
        int k = ks * 32 + (lane >> 4) * 8 + e;
        wsw[i] = f2bf(w1[k * 384 + n]);
    } else if (i < 110592) {               // w2f frag-linear
        int j = i - 73728;
        int e = j & 7, f = j >> 3;
        int lane = f & 63, fid = f >> 6;
        int ks = fid & 1, t = fid >> 1;
        int nt = t % 6, ck = t / 6;
        int n = nt * 16 + (lane & 15);
        int k = ck * 64 + ks * 32 + (lane >> 4) * 8 + e;
        wsw[i] = f2bf(w2[k * 96 + n]);
    } else if (i < 159744) {               // bmf: BM in D-frag layout (fp32)
        float* bmf = (float*)(wsw + 110592);
        int j = i - 110592;                // 0..49151
        int r = j & 3, lane = (j >> 2) & 63;
        int fid = j >> 8;                  // 0..191
        int mtnt = fid & 15, t = fid >> 4; // t 0..11
        int mt = mtnt >> 2, nt = mtnt & 3;
        int hd = t % 3, cls = t / 3;
        int m = mt * 16 + (lane >> 4) * 4 + r; if (m > 48) m = 48;
        int n = nt * 16 + (lane & 15);
        float val = 0.f;
        if (n < 49) {
            int it = m / 7, jt = m - it * 7;
            int iu = n / 7, ju = n - iu * 7;
            int li  = (cls & 2) ? (it < 4 ? 1 : 2) : 0;
            int lj  = (cls & 1) ? (jt < 4 ? 1 : 2) : 0;
            int lui = (cls & 2) ? (iu < 4 ? 1 : 2) : 0;
            int luj = (cls & 1) ? (ju < 4 ? 1 : 2) : 0;
            int bidx = (jt - ju + 6) * 13 + (it - iu + 6);
            val = btab[bidx * 3 + hd] + ((li*3+lj) == (lui*3+luj) ? 0.f : -100.f);
        }
        bmf[j] = val;
    }
}

// ---------- K12: fused LN1 + QKV GEMM + attention; block = 1 window ----------
// Q,K stay in LDS (never touch HBM); V -> ovb global, O overwrites V in-place
// (each wave reads its head's V cols before writing O to those cols; in-order
// per wave, cols disjoint across waves). One barrier total; P wave-private.
#define LDQ 104
extern "C" __global__ void __launch_bounds__(256, 2) k12_fused(
    const float* __restrict__ x, const float* __restrict__ g1, const float* __restrict__ b1,
    const unsigned short* __restrict__ qwtf, const float* __restrict__ qb,
    const float* __restrict__ bmf, unsigned short* __restrict__ ovb)
{
    __shared__ unsigned short Qs[64 * LDQ];    // 13312 B
    __shared__ unsigned short Ks[64 * LDQ];    // 13312 B
    __shared__ unsigned short P[3][64 * 72];   // 27648 B  (total 54272)
    const int tid = threadIdx.x, wave = tid >> 6, lane = tid & 63;
    const int l15 = lane & 15, g4 = lane >> 4;
    const int win = blockIdx.x;
    const int g0  = win * NTK;

    // ---- LN1 in frag layout (rows 49-63 clamp-duplicate token 48) ----
    s8v ha[3];
    {
        int row = wave * 16 + l15;
        int tok = row > 48 ? 48 : row;
        ln_frag(x + (size_t)wtok_to_orig(g0 + tok) * CC, g1, b1, g4, ha);
    }

    // ---- QKV GEMM: Q,K -> LDS; V -> ovb ----
    #pragma unroll
    for (int ck = 0; ck < 3; ++ck) {
        fx4 acc[6];
        #pragma unroll
        for (int nt = 0; nt < 6; ++nt) acc[nt] = (fx4){0.f,0.f,0.f,0.f};
        #pragma unroll
        for (int ks = 0; ks < 3; ++ks) {
            #pragma unroll
            for (int nt = 0; nt < 6; ++nt) {
                s8v b = *reinterpret_cast<const s8v*>(
                    &qwtf[(((ck * 6 + nt) * 3 + ks) * 64 + lane) * 8]);
                acc[nt] = MFMA16(ha[ks], b, acc[nt]);
            }
        }
        const int rowb = wave * 16 + g4 * 4;
        if (ck == 0) {
            #pragma unroll
            for (int nt = 0; nt < 6; ++nt) {
                const int col = nt * 16 + l15;
                const float qbc = qb[col] * QKSCALE;
                #pragma unroll
                for (int r = 0; r < 4; ++r)
                    Qs[(rowb + r) * LDQ + col] = f2bf(acc[nt][r] + qbc);
            }
        } else if (ck == 1) {
            #pragma unroll
            for (int nt = 0; nt < 6; ++nt) {
                const int col = nt * 16 + l15;
                const float qbc = qb[96 + col];
                #pragma unroll
                for (int r = 0; r < 4; ++r)
                    Ks[(rowb + r) * LDQ + col] = f2bf(acc[nt][r] + qbc);
            }
        } else {
            #pragma unroll
            for (int nt = 0; nt < 6; ++nt) {
                const int col = nt * 16 + l15;
                const float qbc = qb[192 + col];
                #pragma unroll
                for (int r = 0; r < 4; ++r) {
                    const int rr = rowb + r;
                    if (rr < NTK)
                        ovb[(size_t)(g0 + rr) * 96 + col] = f2bf(acc[nt][r] + qbc);
                }
            }
        }
    }
    __syncthreads();   // Qs/Ks visible; V stores drained (vmcnt(0) before barrier)

    // ---- attention: waves 0..2 = heads 0..2 ----
    if (wave < 3) {
        const int h = wave;
        const int w = win & 63;
        const int cls = (((w >> 3) == 7) ? 2 : 0) + (((w & 7) == 7) ? 1 : 0);
        const float* BMF = bmf + (size_t)(cls * 3 + h) * 4096;
        unsigned short* Ph = &P[h][0];

        s8v aq[4], bk[4];
        #pragma unroll
        for (int mt = 0; mt < 4; ++mt) {
            const int rm = mt * 16 + l15;       // rows 49-63 hold token-48 copies
            aq[mt] = *reinterpret_cast<const s8v*>(&Qs[rm * LDQ + h * 32 + g4 * 8]);
            bk[mt] = *reinterpret_cast<const s8v*>(&Ks[rm * LDQ + h * 32 + g4 * 8]);
        }

        fx4 sc[4][4];
        #pragma unroll
        for (int mt = 0; mt < 4; ++mt)
            #pragma unroll
            for (int nt = 0; nt < 4; ++nt)
                sc[mt][nt] = MFMA16(aq[mt], bk[nt], ((fx4){0.f,0.f,0.f,0.f}));

        #pragma unroll
        for (int mt = 0; mt < 4; ++mt) {
            fx4 bmv[4];
            #pragma unroll
            for (int nt = 0; nt < 4; ++nt)
                bmv[nt] = *reinterpret_cast<const fx4*>(&BMF[((mt * 4 + nt) << 8) + lane * 4]);
            #pragma unroll
            for (int r = 0; r < 4; ++r) {
                float rs1 = 0.f;
                #pragma unroll
                for (int nt = 0; nt < 4; ++nt) {
                    const int n = nt * 16 + l15;
                    float s = sc[mt][nt][r] + bmv[nt][r];
                    float e = (n < NTK) ? __expf(s) : 0.f;
                    sc[mt][nt][r] = e;
                    rs1 += e;
                }
                rs1 += __shfl_xor(rs1, 1); rs1 += __shfl_xor(rs1, 2);
                rs1 += __shfl_xor(rs1, 4); rs1 += __shfl_xor(rs1, 8);
                const float iv1 = 1.f / rs1;
                float rs2 = 0.f;
                #pragma unroll
                for (int nt = 0; nt < 4; ++nt) {
                    const int n = nt * 16 + l15;
                    float e2 = (n < NTK) ? __expf(sc[mt][nt][r] * iv1) : 0.f;
                    sc[mt][nt][r] = e2;
                    rs2 += e2;
                }
                rs2 += __shfl_xor(rs2, 1); rs2 += __shfl_xor(rs2, 2);
                rs2 += __shfl_xor(rs2, 4); rs2 += __shfl_xor(rs2, 8);
                const float iv2 = 1.f / rs2;
                const int m = mt * 16 + g4 * 4 + r;
                #pragma unroll
                for (int nt = 0; nt < 4; ++nt)
                    Ph[m * 72 + nt * 16 + l15] = f2bf(sc[mt][nt][r] * iv2);
            }
        }
        // (no barrier: P[h] is wave-private)

        fx4 oc[4][2];
        #pragma unroll
        for (int mt = 0; mt < 4; ++mt) { oc[mt][0] = (fx4){0.f,0.f,0.f,0.f}; oc[mt][1] = (fx4){0.f,0.f,0.f,0.f}; }
        #pragma unroll
        for (int ks = 0; ks < 2; ++ks) {
            s8v vb[2];
            #pragma unroll
            for (int nt = 0; nt < 2; ++nt) {
                union { s8v v; unsigned short u[8]; } pv;
                #pragma unroll
                for (int j = 0; j < 8; ++j) {
                    int tok = ks * 32 + g4 * 8 + j; if (tok > 48) tok = 48;
                    pv.u[j] = ovb[(size_t)(g0 + tok) * 96 + h * 32 + nt * 16 + l15];
                }
                vb[nt] = pv.v;
            }
            #pragma unroll
            for (int mt = 0; mt < 4; ++mt) {
                s8v pa = *reinterpret_cast<const s8v*>(&Ph[(mt * 16 + l15) * 72 + ks * 32 + g4 * 8]);
                oc[mt][0] = MFMA16(pa, vb[0], oc[mt][0]);
                oc[mt][1] = MFMA16(pa, vb[1], oc[mt][1]);
            }
        }
        // O overwrites this head's V cols (all V reads for this wave precede)
        #pragma unroll
        for (int mt = 0; mt < 4; ++mt) {
            #pragma unroll
            for (int r = 0; r < 4; ++r) {
                const int m = mt * 16 + g4 * 4 + r;
                if (m < NTK) {
                    ovb[(size_t)(g0 + m) * 96 + h * 32 + l15]      = f2bf(oc[mt][0][r]);
                    ovb[(size_t)(g0 + m) * 96 + h * 32 + 16 + l15] = f2bf(oc[mt][1][r]);
                }
            }
        }
    }
}

// ---------- K23: fused proj + residual + LN2 + MLP + residual (R22 form) ----------
#define LDA 72
#define LDX2 100
extern "C" __global__ void __launch_bounds__(256, 3) k23_fused(
    const unsigned short* __restrict__ ovb, const unsigned short* __restrict__ pwtf,
    const float* __restrict__ pb, const float* __restrict__ x,
    const float* __restrict__ g2, const float* __restrict__ b2,
    const unsigned short* __restrict__ w1f, const float* __restrict__ bf1,
    const unsigned short* __restrict__ w2f, const float* __restrict__ bf2,
    float* __restrict__ out)
{
    __shared__ float X2[64][LDX2];             // 25600 B, wave-private rows
    __shared__ unsigned short Ac[64 * LDA];    // 9216 B  (total 34816)
    const int tid = threadIdx.x, wave = tid >> 6, lane = tid & 63;
    const int l15 = lane & 15, g4 = lane >> 4;
    const int row0 = blockIdx.x * 64 + wave * 16;   // orig-token rows

    s8v a[3];
    {
        const int t = row0 + l15;
        const int b = t / (HH * WWI), rc = t - b * (HH * WWI);
        const int orr = rc / WWI, occ = rc - orr * WWI;
        int wr = orr + (HH - SHF); if (wr >= HH) wr -= HH;
        int wc = occ + (WWI - SHF); if (wc >= WWI) wc -= WWI;
        const int wtok = (b * 64 + (wr / WSZ) * 8 + (wc / WSZ)) * NTK
                         + (wr % WSZ) * WSZ + (wc % WSZ);
        const unsigned short* arow = ovb + (size_t)wtok * 96 + g4 * 8;
        a[0] = *reinterpret_cast<const s8v*>(arow);
        a[1] = *reinterpret_cast<const s8v*>(arow + 32);
        a[2] = *reinterpret_cast<const s8v*>(arow + 64);
    }
    {
        fx4 acc[6];
        #pragma unroll
        for (int nt = 0; nt < 6; ++nt) acc[nt] = (fx4){0.f,0.f,0.f,0.f};
        #pragma unroll
        for (int ks = 0; ks < 3; ++ks) {
            #pragma unroll
            for (int nt = 0; nt < 6; ++nt) {
                s8v b = *reinterpret_cast<const s8v*>(&pwtf[((nt * 3 + ks) * 64 + lane) * 8]);
                acc[nt] = MFMA16(a[ks], b, acc[nt]);
            }
        }
        #pragma unroll
        for (int nt = 0; nt < 6; ++nt) {
            const int col = nt * 16 + l15;
            const float pbc = pb[col];
            #pragma unroll
            for (int r = 0; r < 4; ++r) {
                const int tr = row0 + g4 * 4 + r;
                X2[wave * 16 + g4 * 4 + r][col] = acc[nt][r] + pbc + x[(size_t)tr * CC + col];
            }
        }
    }

    s8v ha[3];
    ln_frag(&X2[wave * 16 + l15][0], g2, b2, g4, ha);

    fx4 oacc[6];
    #pragma unroll
    for (int nt = 0; nt < 6; ++nt) oacc[nt] = (fx4){0.f,0.f,0.f,0.f};

    #pragma unroll 1
    for (int ck = 0; ck < 6; ++ck) {
        fx4 a1[4];
        #pragma unroll
        for (int nt = 0; nt < 4; ++nt) a1[nt] = (fx4){0.f,0.f,0.f,0.f};
        #pragma unroll
        for (int ks = 0; ks < 3; ++ks) {
            #pragma unroll
            for (int nt = 0; nt < 4; ++nt) {
                s8v b = *reinterpret_cast<const s8v*>(
                    &w1f[(((ck * 4 + nt) * 3 + ks) * 64 + lane) * 8]);
                a1[nt] = MFMA16(ha[ks], b, a1[nt]);
            }
        }
        #pragma unroll
        for (int nt = 0; nt < 4; ++nt) {
            const float bb = bf1[ck * 64 + nt * 16 + l15];
            #pragma unroll
            for (int r = 0; r < 4; ++r) {
                float v0 = a1[nt][r] + bb;
                Ac[(wave*16 + g4*4 + r) * LDA + nt*16 + l15] = f2bf(gelu_t(gelu_t(v0)));
            }
        }
        #pragma unroll
        for (int ks = 0; ks < 2; ++ks) {
            s8v aa = *reinterpret_cast<const s8v*>(&Ac[(wave*16 + l15)*LDA + ks*32 + g4*8]);
            #pragma unroll
            for (int nt = 0; nt < 6; ++nt) {
                s8v b = *reinterpret_cast<const s8v*>(
                    &w2f[(((ck * 6 + nt) * 2 + ks) * 64 + lane) * 8]);
                oacc[nt] = MFMA16(aa, b, oacc[nt]);
            }
        }
    }

    const int rowb = row0 + g4 * 4;
    #pragma unroll
    for (int nt = 0; nt < 6; ++nt) {
        const int col = nt * 16 + l15;
        const float bb = bf2[col];
        #pragma unroll
        for (int r = 0; r < 4; ++r) {
            out[(size_t)(rowb + r) * CC + col] =
                X2[wave * 16 + g4 * 4 + r][col] + oacc[nt][r] + bb;
        }
    }
}

extern "C" void kernel_launch(void* const* d_in, const int* in_sizes, int n_in,
                              void* d_out, int out_size, void* d_ws, size_t ws_size,
                              hipStream_t stream)
{
    const float* x    = (const float*)d_in[0];
    const float* n1g  = (const float*)d_in[1];
    const float* n1b  = (const float*)d_in[2];
    const float* qw   = (const float*)d_in[3];
    const float* qb   = (const float*)d_in[4];
    const float* btab = (const float*)d_in[5];
    const float* pw   = (const float*)d_in[6];
    const float* pb   = (const float*)d_in[7];
    const float* n2g  = (const float*)d_in[8];
    const float* n2b  = (const float*)d_in[9];
    const float* w1   = (const float*)d_in[10];
    const float* bf1  = (const float*)d_in[11];
    const float* w2   = (const float*)d_in[12];
    const float* bf2  = (const float*)d_in[13];
    float* out = (float*)d_out;

    unsigned short* ovb  = (unsigned short*)d_ws;                 // TOT*96 bf16 = 19.3 MB (V then O)
    unsigned short* wbf  = ovb + (size_t)TOT * 96;
    unsigned short* qwtf = wbf;                                   // 27648 frag-linear
    unsigned short* pwtf = qwtf + 27648;                          // 9216 frag-linear
    unsigned short* w1f  = pwtf + 9216;                           // 36864 frag-linear
    unsigned short* w2f  = w1f + 36864;                           // 36864 frag-linear
    float* bmf = (float*)(wbf + 110592);                          // 49152 fp32 (D-frag)

    p0_prep  <<<624, 256, 0, stream>>>(qw, pw, w1, w2, btab, wbf);
    k12_fused<<<BB*NWIN, 256, 0, stream>>>(x, n1g, n1b, qwtf, qb, bmf, ovb);
    k23_fused<<<TOT/64, 256, 0, stream>>>(ovb, pwtf, pb, x, n2g, n2b,
                                          w1f, bf1, w2f, bf2, out);
}